// Round 5
// baseline (491.432 us; speedup 1.0000x reference)
//
#include <hip/hip_runtime.h>
#include <hip/hip_bf16.h>

// ---------------- problem constants ----------------
constexpr int Bc  = 4;
constexpr int Sc  = 1024;
constexpr int Hc  = 1536;
constexpr int NHc = 24;
constexpr int P2c = 512;            // 2*ATT_SPAN
constexpr int MX  = Bc * Sc;        // 4096 rows of X
constexpr int MA  = MX + P2c;       // 4608 rows of [X ; rel_emb]
constexpr int N3  = 3 * Hc;         // 4608 output cols (q|k|v)
constexpr float INV_SCALE = 0.07216878364870323f;  // 1/sqrt(64*3)

using f32x4  = __attribute__((ext_vector_type(4))) float;
using bf16x8 = __attribute__((ext_vector_type(8))) short;
using i32x4  = __attribute__((ext_vector_type(4))) int;
using u16x8  = __attribute__((ext_vector_type(8))) unsigned short;
using u16x4  = __attribute__((ext_vector_type(4))) unsigned short;
typedef unsigned short u16;

#define DEV __device__ __forceinline__

DEV float bf2f(u16 u) { return __uint_as_float(((unsigned)u) << 16); }
DEV u16   f2bf(float f) { return __builtin_bit_cast(unsigned short, __float2bfloat16(f)); }
DEV void  bar() { __builtin_amdgcn_s_barrier(); asm volatile("" ::: "memory"); }

#if defined(__has_builtin)
#if __has_builtin(__builtin_amdgcn_global_load_lds)
#define HAVE_GLL 1
#endif
#endif
#ifndef HAVE_GLL
#define HAVE_GLL 0
#endif

// Stage 32 rows x 64 bf16 cols of a row-major (stride ldk) global tile into LDS.
DEV void stage32(u16* lds, const u16* g, int ldk, int lane) {
#pragma unroll
  for (int c = 0; c < 4; ++c) {
    const int row   = c * 8 + (lane >> 3);
    const int gslot = (lane & 7) ^ (row & 7);          // pre-swizzled source (rule 21)
    const u16* gp = g + (size_t)row * ldk + gslot * 8;
#if HAVE_GLL
    __builtin_amdgcn_global_load_lds(
        (const __attribute__((address_space(1))) void*)gp,
        (__attribute__((address_space(3))) void*)(lds + c * 8 * 64),
        16, 0, 0);
#else
    i32x4 v = *(const i32x4*)gp;
    *(i32x4*)(lds + row * 64 + (lane & 7) * 8) = v;
#endif
  }
}

DEV bf16x8 ldsFrag(const u16* base, int row, int kh, int lhi) {
  const int idx = row * 64 + ((kh * 32 + lhi * 8) ^ ((row & 7) * 8));
  return *(const bf16x8*)(base + idx);
}

// ---------------- gemm256k: 256x192 tile, 8 waves, dbuf LDS, counted vmcnt ----------------
// C[M=4608, N=4608] = A[M,1536] @ Bt[N,1536]^T; MODE0 epilogue (bias + scale, bf16 out).
__global__ __launch_bounds__(512, 2) void gemm256k(
    const u16* __restrict__ A, const u16* __restrict__ Bt,
    const float* __restrict__ bias, u16* __restrict__ outb)
{
  constexpr int BM = 256, BN = 192;
  __shared__ alignas(16) u16 As[2][BM * 64];   // 64 KB
  __shared__ alignas(16) u16 Bs[2][BN * 64];   // 48 KB
  const int tid = threadIdx.x, wid = tid >> 6, lane = tid & 63;
  const int wr = wid >> 2, wc = wid & 3;       // 2 x 4 wave grid
  const int l15 = lane & 15, lhi = lane >> 4;

  // bijective XCD swizzle over 432 blocks (432 % 8 == 0 -> simple form)
  int id = blockIdx.x;
  id = (id & 7) * 54 + (id >> 3);
  const int m0 = (id / 24) * BM, n0 = (id % 24) * BN;

  // staging: chunk = 64 rows x 64 cols, one 16B gload_lds per thread
  const int srow = tid >> 3;                   // 0..63
  const int gsl  = (tid & 7) ^ (srow & 7);     // pre-swizzled source slot

  auto stageA = [&](int buf, int ck, int k0) {
    const u16* gp = A + (size_t)(m0 + ck * 64 + srow) * 1536 + k0 + gsl * 8;
#if HAVE_GLL
    __builtin_amdgcn_global_load_lds(
        (const __attribute__((address_space(1))) void*)gp,
        (__attribute__((address_space(3))) void*)(&As[buf][ck * 4096 + wid * 512]),
        16, 0, 0);
#else
    *(i32x4*)(&As[buf][ck * 4096 + srow * 64 + (tid & 7) * 8]) = *(const i32x4*)gp;
#endif
  };
  auto stageB = [&](int buf, int ck, int k0) {
    const u16* gp = Bt + (size_t)(n0 + ck * 64 + srow) * 1536 + k0 + gsl * 8;
#if HAVE_GLL
    __builtin_amdgcn_global_load_lds(
        (const __attribute__((address_space(1))) void*)gp,
        (__attribute__((address_space(3))) void*)(&Bs[buf][ck * 4096 + wid * 512]),
        16, 0, 0);
#else
    *(i32x4*)(&Bs[buf][ck * 4096 + srow * 64 + (tid & 7) * 8]) = *(const i32x4*)gp;
#endif
  };

  f32x4 acc[8][3] = {};

  // prologue: stage K-tile 0 into buf 0 (7 loads/thread in flight)
  stageA(0, 0, 0); stageA(0, 1, 0); stageA(0, 2, 0); stageA(0, 3, 0);
  stageB(0, 0, 0); stageB(0, 1, 0); stageB(0, 2, 0);

  int cur = 0;
#pragma unroll 1
  for (int kt = 0; kt < 24; ++kt) {
    const int nk0 = kt * 64 + 64;
    const bool more = (kt < 23);
    const int nb = cur ^ 1;

    // ---- phase 0: vmcnt gate for this K-tile, then (A mg0, B) @ kh0 ----
    if (more) { stageA(nb, 0, nk0); stageA(nb, 1, nk0); }
    if (more) asm volatile("s_waitcnt vmcnt(2)" ::: "memory");
    else      asm volatile("s_waitcnt vmcnt(0)" ::: "memory");
    bar();
    bf16x8 bf[3], af[4];
#pragma unroll
    for (int nt = 0; nt < 3; ++nt) bf[nt] = ldsFrag(Bs[cur], wc * 48 + nt * 16 + l15, 0, lhi);
#pragma unroll
    for (int mt = 0; mt < 4; ++mt) af[mt] = ldsFrag(As[cur], wr * 128 + mt * 16 + l15, 0, lhi);
    __builtin_amdgcn_s_setprio(1);
#pragma unroll
    for (int mt = 0; mt < 4; ++mt)
#pragma unroll
      for (int nt = 0; nt < 3; ++nt)
        acc[mt][nt] = __builtin_amdgcn_mfma_f32_16x16x32_bf16(af[mt], bf[nt], acc[mt][nt], 0, 0, 0);
    __builtin_amdgcn_s_setprio(0);
    if (more) { stageA(nb, 2, nk0); stageA(nb, 3, nk0); }
    bar();

    // ---- phase 1: A mg1 @ kh0 (B frags reused) ----
#pragma unroll
    for (int mt = 0; mt < 4; ++mt) af[mt] = ldsFrag(As[cur], wr * 128 + 64 + mt * 16 + l15, 0, lhi);
    __builtin_amdgcn_s_setprio(1);
#pragma unroll
    for (int mt = 0; mt < 4; ++mt)
#pragma unroll
      for (int nt = 0; nt < 3; ++nt)
        acc[4 + mt][nt] = __builtin_amdgcn_mfma_f32_16x16x32_bf16(af[mt], bf[nt], acc[4 + mt][nt], 0, 0, 0);
    __builtin_amdgcn_s_setprio(0);
    if (more) { stageB(nb, 0, nk0); stageB(nb, 1, nk0); }
    bar();

    // ---- phase 2: (A mg0, B) @ kh1 ----
#pragma unroll
    for (int nt = 0; nt < 3; ++nt) bf[nt] = ldsFrag(Bs[cur], wc * 48 + nt * 16 + l15, 1, lhi);
#pragma unroll
    for (int mt = 0; mt < 4; ++mt) af[mt] = ldsFrag(As[cur], wr * 128 + mt * 16 + l15, 1, lhi);
    __builtin_amdgcn_s_setprio(1);
#pragma unroll
    for (int mt = 0; mt < 4; ++mt)
#pragma unroll
      for (int nt = 0; nt < 3; ++nt)
        acc[mt][nt] = __builtin_amdgcn_mfma_f32_16x16x32_bf16(af[mt], bf[nt], acc[mt][nt], 0, 0, 0);
    __builtin_amdgcn_s_setprio(0);
    if (more) { stageB(nb, 2, nk0); }
    bar();

    // ---- phase 3: A mg1 @ kh1 ----
#pragma unroll
    for (int mt = 0; mt < 4; ++mt) af[mt] = ldsFrag(As[cur], wr * 128 + 64 + mt * 16 + l15, 1, lhi);
    __builtin_amdgcn_s_setprio(1);
#pragma unroll
    for (int mt = 0; mt < 4; ++mt)
#pragma unroll
      for (int nt = 0; nt < 3; ++nt)
        acc[4 + mt][nt] = __builtin_amdgcn_mfma_f32_16x16x32_bf16(af[mt], bf[nt], acc[4 + mt][nt], 0, 0, 0);
    __builtin_amdgcn_s_setprio(0);
    bar();

    cur ^= 1;
  }

  // ---- epilogue: bias + scale, bf16 out ----
#pragma unroll
  for (int mg = 0; mg < 8; ++mg)
#pragma unroll
    for (int nt = 0; nt < 3; ++nt) {
      const int gn = n0 + wc * 48 + nt * 16 + l15;
      const float bs = bias[gn];
      const float sc = gn < Hc ? INV_SCALE : 1.f;
#pragma unroll
      for (int r = 0; r < 4; ++r) {
        const int gm = m0 + wr * 128 + mg * 16 + (lhi << 2) + r;
        outb[(size_t)gm * 4608 + gn] = f2bf((acc[mg][nt][r] + bs) * sc);
      }
    }
}

// ---------------- GEMM 128x128 (kept for out-proj): MODE 1 epilogue ----------------
__global__ __launch_bounds__(256) void gemm128o(
    const u16* __restrict__ A, const u16* __restrict__ Bt,
    const float* __restrict__ bias, const float* __restrict__ resid,
    float* __restrict__ outf, int ldo)
{
  __shared__ alignas(16) u16 As[128 * 64];
  __shared__ alignas(16) u16 Bs[128 * 64];
  const int tid = threadIdx.x, wid = tid >> 6, lane = tid & 63;
  const int wr = wid >> 1, wc = wid & 1;
  const int l15 = lane & 15, lhi = lane >> 4;
  const int m0 = blockIdx.y * 128, n0 = blockIdx.x * 128;

  f32x4 acc[4][4] = {};
#pragma unroll 1
  for (int kt = 0; kt < 24; ++kt) {
    const int k0 = kt * 64;
    stage32(As + wid * (32 * 64), A  + (size_t)(m0 + wid * 32) * 1536 + k0, 1536, lane);
    stage32(Bs + wid * (32 * 64), Bt + (size_t)(n0 + wid * 32) * 1536 + k0, 1536, lane);
    asm volatile("s_waitcnt vmcnt(0)" ::: "memory");
    __syncthreads();
#pragma unroll
    for (int kh = 0; kh < 2; ++kh) {
      bf16x8 af[4], bfv[4];
#pragma unroll
      for (int mt = 0; mt < 4; ++mt) af[mt]  = ldsFrag(As, wr * 64 + mt * 16 + l15, kh, lhi);
#pragma unroll
      for (int nt = 0; nt < 4; ++nt) bfv[nt] = ldsFrag(Bs, wc * 64 + nt * 16 + l15, kh, lhi);
#pragma unroll
      for (int mt = 0; mt < 4; ++mt)
#pragma unroll
        for (int nt = 0; nt < 4; ++nt)
          acc[mt][nt] = __builtin_amdgcn_mfma_f32_16x16x32_bf16(af[mt], bfv[nt], acc[mt][nt], 0, 0, 0);
    }
    __syncthreads();
  }
#pragma unroll
  for (int mt = 0; mt < 4; ++mt)
#pragma unroll
    for (int nt = 0; nt < 4; ++nt) {
      const int gn = n0 + wc * 64 + nt * 16 + l15;
      const float bs = bias[gn];
#pragma unroll
      for (int r = 0; r < 4; ++r) {
        const int gm = m0 + wr * 64 + mt * 16 + lhi * 4 + r;
        outf[(size_t)gm * ldo + gn] = acc[mt][nt][r] + bs + resid[(size_t)gm * ldo + gn];
      }
    }
}

// ---------------- prep: bias concat, valid vector, single delta->index table ----------------
__global__ __launch_bounds__(256) void prep_misc(
    const float* __restrict__ bq, const float* __restrict__ bk, const float* __restrict__ bv,
    const int* __restrict__ am, const int* __restrict__ rp,
    float* __restrict__ bias, int* __restrict__ valid, u16* __restrict__ tbl)
{
  const int TOT = N3 + MX + 2047;
  for (int i = blockIdx.x * 256 + threadIdx.x; i < TOT; i += gridDim.x * 256) {
    if (i < N3) {
      bias[i] = i < Hc ? bq[i] : (i < 2 * Hc ? bk[i - Hc] : bv[i - 2 * Hc]);
    } else if (i < N3 + MX) {
      const int j = i - N3, b = j >> 10, s = j & 1023;
      valid[j] = am[(size_t)b * Sc * Sc + (size_t)s * Sc + s];
    } else {
      const int t = i - (N3 + MX), d = t - 1023;                 // delta = q - k
      int v = (d >= 0 ? rp[(size_t)d * Sc] : rp[-d]) + 256;      // clip(bucket(d)+256)
      v = v < 0 ? 0 : (v > 511 ? 511 : v);
      tbl[t] = (u16)v;
    }
  }
}

// ---------------- lens: per-batch valid length (prefix property) ----------------
__global__ void len_kernel(const int* __restrict__ valid, int* __restrict__ LENS)
{
  const int tid = threadIdx.x, wid = tid >> 6, lane = tid & 63;   // wid = b
  int s = 0;
#pragma unroll
  for (int j = 0; j < 16; ++j) s += valid[wid * Sc + j * 64 + lane];
#pragma unroll
  for (int off = 1; off <= 32; off <<= 1) s += __shfl_xor(s, off);
  if (lane == 0) LENS[wid] = s;
}

// ---------------- cast [X ; rel_emb] -> bf16 A-matrix ----------------
__global__ __launch_bounds__(256) void cast_x(const float* __restrict__ hs,
                                              const float* __restrict__ rel,
                                              u16* __restrict__ A)
{
  const size_t total = (size_t)MA * Hc / 4;
  for (size_t i = (size_t)blockIdx.x * 256 + threadIdx.x; i < total; i += (size_t)gridDim.x * 256) {
    const size_t e = i * 4;
    const int row = (int)(e / Hc), col = (int)(e % Hc);
    const float* s = row < MX ? hs + (size_t)row * Hc + col : rel + (size_t)(row - MX) * Hc + col;
    f32x4 v = *(const f32x4*)s;
    u16x4 o = { f2bf(v[0]), f2bf(v[1]), f2bf(v[2]), f2bf(v[3]) };
    *(u16x4*)(A + e) = o;
  }
}

// ---------------- transpose-cast weights ----------------
__global__ void transpose_cast(const float* __restrict__ Wq, const float* __restrict__ Wk,
                               const float* __restrict__ Wv, const float* __restrict__ Wo,
                               u16* __restrict__ WT, u16* __restrict__ WOT)
{
  const int z = blockIdx.z;
  const float* src = z == 0 ? Wq : z == 1 ? Wk : z == 2 ? Wv : Wo;
  u16* dst = z == 3 ? WOT : WT + (size_t)z * Hc * Hc;
  __shared__ float t[32][33];
  const int tx = threadIdx.x, ty = threadIdx.y;
  const int kb = blockIdx.y * 32, nb = blockIdx.x * 32;
#pragma unroll
  for (int i = 0; i < 4; ++i)
    t[ty + i * 8][tx] = src[(size_t)(kb + ty + i * 8) * Hc + nb + tx];
  __syncthreads();
#pragma unroll
  for (int i = 0; i < 4; ++i)
    dst[(size_t)(nb + ty + i * 8) * Hc + kb + tx] = f2bf(t[tx][ty + i * 8]);
}

// ---------------- relmat3: c2p[q][p] (var0) and p2cT[p][k] (var1), K=64 GEMMs ----------------
__global__ __launch_bounds__(256) void relmat3(const u16* __restrict__ QKVP,
    u16* __restrict__ c2p, u16* __restrict__ p2cT, int bh_base)
{
  const int z = blockIdx.y, lbh = z >> 1, var = z & 1;
  const int bh = bh_base + lbh, b = bh / NHc, h = bh % NHc;
  const int t = blockIdx.x;
  const int tid = threadIdx.x, wid = tid >> 6, lane = tid & 63;
  const int wr = wid >> 1, wc = wid & 1;
  const int l15 = lane & 15, lhi = lane >> 4;

  int m0, n0, ldo;
  size_t arowb, browb;
  u16* out;
  if (var == 0) {            // c2p[q][p]: M=1024 (q), N=512 (p)
    m0 = (t >> 2) * 64; n0 = (t & 3) * 128; ldo = P2c;
    arowb = (size_t)b * Sc + m0;  browb = (size_t)MX + n0;
    out = c2p + (size_t)lbh * Sc * P2c;
  } else {                   // p2cT[cc][k]: M=512 (cc), N=1024 (k)
    m0 = (t >> 3) * 64; n0 = (t & 7) * 128; ldo = Sc;
    arowb = (size_t)MX + m0;      browb = (size_t)b * Sc + n0;
    out = p2cT + (size_t)lbh * P2c * Sc;
  }
  const int acol = h * 64;
  const int bcol = Hc + h * 64;

  f32x4 acc[2][4] = {};
#pragma unroll
  for (int kh = 0; kh < 2; ++kh) {
    bf16x8 a[2], bb[4];
#pragma unroll
    for (int mt = 0; mt < 2; ++mt)
      a[mt] = *(const bf16x8*)(QKVP + (arowb + wr * 32 + mt * 16 + l15) * 4608
                               + acol + kh * 32 + lhi * 8);
#pragma unroll
    for (int nt = 0; nt < 4; ++nt)
      bb[nt] = *(const bf16x8*)(QKVP + (browb + wc * 64 + nt * 16 + l15) * 4608
                                + bcol + kh * 32 + lhi * 8);
#pragma unroll
    for (int mt = 0; mt < 2; ++mt)
#pragma unroll
      for (int nt = 0; nt < 4; ++nt)
        acc[mt][nt] = __builtin_amdgcn_mfma_f32_16x16x32_bf16(a[mt], bb[nt], acc[mt][nt], 0, 0, 0);
  }
#pragma unroll
  for (int mt = 0; mt < 2; ++mt)
#pragma unroll
    for (int nt = 0; nt < 4; ++nt)
#pragma unroll
      for (int r = 0; r < 4; ++r) {
        const int mm = m0 + wr * 32 + mt * 16 + (lhi << 2) + r;
        const int nn = n0 + wc * 64 + nt * 16 + l15;
        out[(size_t)mm * ldo + nn] = f2bf(acc[mt][nt][r]);
      }
}

// ---------------- flash v5: LDS K/V + rel-gathers pipelined one tile ahead ----------------
DEV int svz(int d) { return ((d ^ (d >> 3)) & 7) << 3; }   // V swizzle: 2-way both sides

__global__ __launch_bounds__(256) void flash5(
    const u16* __restrict__ QKVP, const u16* __restrict__ c2p, const u16* __restrict__ p2cT,
    const int* __restrict__ LENS, const u16* __restrict__ tblG,
    u16* __restrict__ ctx, int bh_base, int chunkC)
{
  int id = blockIdx.x;
  const int grid = chunkC * 16;
  if ((grid & 7) == 0) {                    // bijective XCD swizzle: bh-contiguous per XCD
    const int cpx = grid >> 3;
    id = (id & 7) * cpx + (id >> 3);
  }
  const int lbh = id >> 4, qi = id & 15;
  const int bh = bh_base + lbh, b = bh / NHc, h = bh % NHc;
  const int tid = threadIdx.x, wid = tid >> 6, lane = tid & 63;
  const int l15 = lane & 15, lhi = lane >> 4, lhi4 = lhi * 4;
  const int qrb = qi * 64 + wid * 16;
  const int len = LENS[b], nkt = (len + 63) >> 6;

  __shared__ u16 Tt[2048];
  __shared__ alignas(16) u16 Kt[64 * 64];
  __shared__ alignas(16) u16 Vt[64 * 64];
  __shared__ alignas(16) u16 Pl[4][16 * 64];

  for (int i = tid; i < 2047; i += 256) Tt[i] = tblG[i];

  bf16x8 aq[2];
#pragma unroll
  for (int kh = 0; kh < 2; ++kh)
    aq[kh] = *(const bf16x8*)(QKVP + (size_t)(b * Sc + qrb + l15) * 4608 + h * 64 + kh * 32 + lhi * 8);

  const int kr = tid >> 2, dc = (tid & 3) * 16;
  const int sk = (kr & 7) * 8;
  const u16* Kg = QKVP + (size_t)b * Sc * 4608 + Hc + h * 64;
  const u16* Vg = QKVP + (size_t)b * Sc * 4608 + 2 * Hc + h * 64;

  auto writeKV = [&](u16x8 ka, u16x8 kb, u16x8 va, u16x8 vb) {
    *(u16x8*)(Kt + kr * 64 + (dc ^ sk))       = ka;
    *(u16x8*)(Kt + kr * 64 + ((dc ^ sk) ^ 8)) = kb;
#pragma unroll
    for (int i = 0; i < 8; ++i) { const int d = dc + i;     Vt[d * 64 + (kr ^ svz(d))] = va[i]; }
#pragma unroll
    for (int i = 0; i < 8; ++i) { const int d = dc + 8 + i; Vt[d * 64 + (kr ^ svz(d))] = vb[i]; }
  };

  { // prologue: K/V tile 0
    const size_t ro = (size_t)kr * 4608 + dc;
    u16x8 ka = *(const u16x8*)(Kg + ro), kb = *(const u16x8*)(Kg + ro + 8);
    u16x8 va = *(const u16x8*)(Vg + ro), vb = *(const u16x8*)(Vg + ro + 8);
    writeKV(ka, kb, va, vb);
  }
  __syncthreads();                          // Tt + tile 0 visible

  const u16* c2pB  = c2p  + (size_t)lbh * Sc * P2c;
  const u16* p2cTB = p2cT + (size_t)lbh * P2c * Sc;
  u16* myP = Pl[wid];
  f32x4 o_acc[4] = {};
  float m_arr[4], l_arr[4];
#pragma unroll
  for (int r = 0; r < 4; ++r) { m_arr[r] = -1e30f; l_arr[r] = 0.f; }

  // rel gathers for tile 0 (Tt read via __syncthreads-protected path above)
  u16 rc[16], rp[16];
#pragma unroll
  for (int j = 0; j < 4; ++j)
#pragma unroll
    for (int r = 0; r < 4; ++r) {
      const int q = qrb + lhi4 + r;
      const int k = j * 16 + l15;
      const int cc = Tt[q - k + 1023];
      rc[j * 4 + r] = c2pB[(size_t)q * P2c + cc];
      rp[j * 4 + r] = p2cTB[(size_t)cc * Sc + k];
    }

  for (int kt = 0; kt < nkt; ++kt) {
    const int k0 = kt * 64;
    const bool more = (kt + 1 < nkt);
    u16x8 nka, nkb, nva, nvb;
    if (more) {                              // T14: next K/V tile loads issued early
      const size_t ro = (size_t)(k0 + 64 + kr) * 4608 + dc;
      nka = *(const u16x8*)(Kg + ro); nkb = *(const u16x8*)(Kg + ro + 8);
      nva = *(const u16x8*)(Vg + ro); nvb = *(const u16x8*)(Vg + ro + 8);
    }
    // T14 for rel gathers: issue tile kt+1's 32 scalar loads now; consume next iter
    u16 nrc[16], nrp[16];
    if (more) {
#pragma unroll
      for (int j = 0; j < 4; ++j)
#pragma unroll
        for (int r = 0; r < 4; ++r) {
          const int q = qrb + lhi4 + r;
          const int k = k0 + 64 + j * 16 + l15;
          const int cc = Tt[q - k + 1023];
          nrc[j * 4 + r] = c2pB[(size_t)q * P2c + cc];
          nrp[j * 4 + r] = p2cTB[(size_t)cc * Sc + k];
        }
    }

    // S = Q K^T from LDS (rows q, cols k)
    f32x4 s[4];
    __builtin_amdgcn_s_setprio(1);
#pragma unroll
    for (int j = 0; j < 4; ++j) {
      f32x4 sv = {};
#pragma unroll
      for (int kh = 0; kh < 2; ++kh) {
        bf16x8 bk = ldsFrag(Kt, j * 16 + l15, kh, lhi);
        sv = __builtin_amdgcn_mfma_f32_16x16x32_bf16(aq[kh], bk, sv, 0, 0, 0);
      }
      s[j] = sv;
    }
    __builtin_amdgcn_s_setprio(0);

    float p[4][4];
#pragma unroll
    for (int j = 0; j < 4; ++j) {
      const bool kv = (k0 + j * 16 + l15) < len;
#pragma unroll
      for (int r = 0; r < 4; ++r)
        p[j][r] = kv ? (s[j][r] + bf2f(rc[j * 4 + r]) + bf2f(rp[j * 4 + r])) : -1e30f;
    }

    float resc[4];
#pragma unroll
    for (int r = 0; r < 4; ++r) {
      float mx = fmaxf(fmaxf(p[0][r], p[1][r]), fmaxf(p[2][r], p[3][r]));
#pragma unroll
      for (int off = 1; off <= 8; off <<= 1) mx = fmaxf(mx, __shfl_xor(mx, off));
      const float mnew = fmaxf(m_arr[r], mx);
      const float sc = __expf(m_arr[r] - mnew);
      float rs = 0.f;
#pragma unroll
      for (int j = 0; j < 4; ++j) { p[j][r] = __expf(p[j][r] - mnew); rs += p[j][r]; }
#pragma unroll
      for (int off = 1; off <= 8; off <<= 1) rs += __shfl_xor(rs, off);
      l_arr[r] = l_arr[r] * sc + rs;
      m_arr[r] = mnew;
      resc[r] = sc;
    }
#pragma unroll
    for (int jd = 0; jd < 4; ++jd)
#pragma unroll
      for (int r = 0; r < 4; ++r) o_acc[jd][r] *= resc[r];

    // P strip (scalar LDS writes, row-XOR swizzle)
#pragma unroll
    for (int j = 0; j < 4; ++j)
#pragma unroll
      for (int r = 0; r < 4; ++r) {
        const int row = lhi4 + r, col = j * 16 + l15;
        myP[row * 64 + (col ^ ((row & 7) * 8))] = f2bf(p[j][r]);
      }

    // PV: O[q][d] += P[q][k] V[k][d]
    __builtin_amdgcn_s_setprio(1);
#pragma unroll
    for (int kh = 0; kh < 2; ++kh) {
      bf16x8 pa = *(const bf16x8*)(myP + l15 * 64 + ((kh * 32 + lhi * 8) ^ ((l15 & 7) * 8)));
#pragma unroll
      for (int jd = 0; jd < 4; ++jd) {
        const int d = jd * 16 + l15;
        bf16x8 vf = *(const bf16x8*)(Vt + d * 64 + ((kh * 32 + lhi * 8) ^ svz(d)));
        o_acc[jd] = __builtin_amdgcn_mfma_f32_16x16x32_bf16(pa, vf, o_acc[jd], 0, 0, 0);
      }
    }
    __builtin_amdgcn_s_setprio(0);

    __syncthreads();                      // all waves done reading Kt/Vt
    if (more) {
      writeKV(nka, nkb, nva, nvb);
#pragma unroll
      for (int i = 0; i < 16; ++i) { rc[i] = nrc[i]; rp[i] = nrp[i]; }
    }
    __syncthreads();                      // next tile visible
  }

  // epilogue
#pragma unroll
  for (int r = 0; r < 4; ++r) {
    const int q = qrb + lhi4 + r;
    const float inv = (q < len && l_arr[r] > 0.f) ? 1.f / l_arr[r] : 0.f;
#pragma unroll
    for (int jd = 0; jd < 4; ++jd)
      ctx[(size_t)(b * Sc + q) * Hc + h * 64 + jd * 16 + l15] = f2bf(o_acc[jd][r] * inv);
  }
}

// ---------------- row-wise LayerNorm in-place on d_out ----------------
__global__ __launch_bounds__(256) void ln_kernel(float* __restrict__ io,
    const float* __restrict__ g, const float* __restrict__ bta)
{
  const int row = blockIdx.x;
  float* p = io + (size_t)row * Hc;
  const int tid = threadIdx.x, wid = tid >> 6, lane = tid & 63;
  float v[6];
  float s = 0.f;
#pragma unroll
  for (int j = 0; j < 6; ++j) { v[j] = p[tid + j * 256]; s += v[j]; }
#pragma unroll
  for (int off = 1; off <= 32; off <<= 1) s += __shfl_xor(s, off);
  __shared__ float red[4];
  if (lane == 0) red[wid] = s;
  __syncthreads();
  const float mu = (red[0] + red[1] + red[2] + red[3]) * (1.f / Hc);
  float q = 0.f;
#pragma unroll
  for (int j = 0; j < 6; ++j) { const float d = v[j] - mu; q += d * d; }
#pragma unroll
  for (int off = 1; off <= 32; off <<= 1) q += __shfl_xor(q, off);
  __syncthreads();
  if (lane == 0) red[wid] = q;
  __syncthreads();
  const float rstd = rsqrtf((red[0] + red[1] + red[2] + red[3]) * (1.f / Hc) + 1e-7f);
#pragma unroll
  for (int j = 0; j < 6; ++j) {
    const int c = tid + j * 256;
    p[c] = (v[j] - mu) * rstd * g[c] + bta[c];
  }
}

// ---------------- host launcher ----------------
extern "C" void kernel_launch(void* const* d_in, const int* in_sizes, int n_in,
                              void* d_out, int out_size, void* d_ws, size_t ws_size,
                              hipStream_t stream)
{
  (void)in_sizes; (void)n_in; (void)out_size;
  const float* hidden = (const float*)d_in[0];
  const float* relemb = (const float*)d_in[1];
  const float* Wq = (const float*)d_in[2];
  const float* bq = (const float*)d_in[3];
  const float* Wk = (const float*)d_in[4];
  const float* bk = (const float*)d_in[5];
  const float* Wv = (const float*)d_in[6];
  const float* bv = (const float*)d_in[7];
  const float* Wo = (const float*)d_in[8];
  const float* bo = (const float*)d_in[9];
  const float* lng = (const float*)d_in[10];
  const float* lnb = (const float*)d_in[11];
  const int* am = (const int*)d_in[12];
  const int* rp = (const int*)d_in[13];
  float* out = (float*)d_out;

  char* ws = (char*)d_ws;
  size_t off = 0;
  auto alloc = [&](size_t bytes) { size_t r = off; off += (bytes + 255) & ~(size_t)255; return r; };
  const size_t o_qkvp = alloc((size_t)MA * 4608 * 2);
  const size_t o_wt   = alloc((size_t)N3 * Hc * 2);
  const size_t o_wot  = alloc((size_t)Hc * Hc * 2);
  const size_t o_abig = alloc((size_t)MA * Hc * 2);
  const size_t o_bias = alloc((size_t)N3 * 4);
  const size_t o_valid= alloc((size_t)MX * 4);
  const size_t o_tbl  = alloc(2048 * 2);
  const size_t o_lens = alloc(256);
  const size_t fixed  = off;
  const size_t o_rel  = off;

  const size_t perbh = (size_t)Sc * P2c * 2 * 2;   // c2p + p2cT = 2MB per bh
  int c = 96;
  while (c > 1 && fixed + (size_t)c * perbh > ws_size) c >>= 1;

  u16* QKVP = (u16*)(ws + o_qkvp);
  u16* WT   = (u16*)(ws + o_wt);
  u16* WOT  = (u16*)(ws + o_wot);
  u16* ABIG = (u16*)(ws + o_abig);
  u16* CTX  = (u16*)(ws + o_abig);                      // alias: ABIG dead after gemm256k
  float* BIAS = (float*)(ws + o_bias);
  int* VALID  = (int*)(ws + o_valid);
  u16* TBL  = (u16*)(ws + o_tbl);
  int* LENS = (int*)(ws + o_lens);
  u16* C2P  = (u16*)(ws + o_rel);
  u16* P2CT = C2P + (size_t)c * Sc * P2c;

  prep_misc<<<dim3(50), dim3(256), 0, stream>>>(bq, bk, bv, am, rp, BIAS, VALID, TBL);
  len_kernel<<<dim3(1), dim3(256), 0, stream>>>(VALID, LENS);
  cast_x<<<dim3(1728), dim3(256), 0, stream>>>(hidden, relemb, ABIG);
  transpose_cast<<<dim3(48, 48, 4), dim3(32, 8), 0, stream>>>(Wq, Wk, Wv, Wo, WT, WOT);
  gemm256k<<<dim3(432), dim3(512), 0, stream>>>(ABIG, WT, BIAS, QKVP);
  for (int base = 0; base < 96; base += c) {
    relmat3<<<dim3(64, 2 * c), dim3(256), 0, stream>>>(QKVP, C2P, P2CT, base);
    flash5<<<dim3(c * 16), dim3(256), 0, stream>>>(QKVP, C2P, P2CT, LENS, TBL, CTX, base, c);
  }
  gemm128o<<<dim3(12, 32), dim3(256), 0, stream>>>(CTX, WOT, bo, hidden, out, Hc);
  ln_kernel<<<dim3(MX), dim3(256), 0, stream>>>(out, lng, lnb);
}

// Round 6
// 408.167 us; speedup vs baseline: 1.2040x; 1.2040x over previous
//
#include <hip/hip_runtime.h>
#include <hip/hip_bf16.h>

// ---------------- problem constants ----------------
constexpr int Bc  = 4;
constexpr int Sc  = 1024;
constexpr int Hc  = 1536;
constexpr int NHc = 24;
constexpr int P2c = 512;            // 2*ATT_SPAN
constexpr int MX  = Bc * Sc;        // 4096 rows of X
constexpr int MA  = MX + P2c;       // 4608 rows of [X ; rel_emb]
constexpr int N3  = 3 * Hc;         // 4608 output cols (q|k|v)
constexpr float INV_SCALE = 0.07216878364870323f;  // 1/sqrt(64*3)

using f32x4  = __attribute__((ext_vector_type(4))) float;
using bf16x8 = __attribute__((ext_vector_type(8))) short;
using i32x4  = __attribute__((ext_vector_type(4))) int;
using u16x8  = __attribute__((ext_vector_type(8))) unsigned short;
using u16x4  = __attribute__((ext_vector_type(4))) unsigned short;
typedef unsigned short u16;

#define DEV __device__ __forceinline__

DEV float bf2f(u16 u) { return __uint_as_float(((unsigned)u) << 16); }
DEV u16   f2bf(float f) { return __builtin_bit_cast(unsigned short, __float2bfloat16(f)); }

#if defined(__has_builtin)
#if __has_builtin(__builtin_amdgcn_global_load_lds)
#define HAVE_GLL 1
#endif
#endif
#ifndef HAVE_GLL
#define HAVE_GLL 0
#endif

// Stage 32 rows x 64 bf16 cols of a row-major (stride ldk) global tile into LDS.
DEV void stage32(u16* lds, const u16* g, int ldk, int lane) {
#pragma unroll
  for (int c = 0; c < 4; ++c) {
    const int row   = c * 8 + (lane >> 3);
    const int gslot = (lane & 7) ^ (row & 7);          // pre-swizzled source (rule 21)
    const u16* gp = g + (size_t)row * ldk + gslot * 8;
#if HAVE_GLL
    __builtin_amdgcn_global_load_lds(
        (const __attribute__((address_space(1))) void*)gp,
        (__attribute__((address_space(3))) void*)(lds + c * 8 * 64),
        16, 0, 0);
#else
    i32x4 v = *(const i32x4*)gp;
    *(i32x4*)(lds + row * 64 + (lane & 7) * 8) = v;
#endif
  }
}

DEV bf16x8 ldsFrag(const u16* base, int row, int kh, int lhi) {
  const int idx = row * 64 + ((kh * 32 + lhi * 8) ^ ((row & 7) * 8));
  return *(const bf16x8*)(base + idx);
}

// ---------------- GEMM: C[M,N] = A[M,K=1536] @ Bt[N,K]^T  (+ epilogue) ----------------
// MODE 0: out = bf16((acc + bias[n]) * (n<1536 ? 1/sqrt(192) : 1))   (QKV+pos proj)
// MODE 1: out = f32(acc + bias[n] + resid[m,n])                       (out proj + residual)
template <int MODE>
__global__ __launch_bounds__(256) void gemm128(
    const u16* __restrict__ A, const u16* __restrict__ Bt,
    const float* __restrict__ bias, const float* __restrict__ resid,
    u16* __restrict__ outb, float* __restrict__ outf, int ldo)
{
  __shared__ alignas(16) u16 As[128 * 64];
  __shared__ alignas(16) u16 Bs[128 * 64];
  const int tid = threadIdx.x, wid = tid >> 6, lane = tid & 63;
  const int wr = wid >> 1, wc = wid & 1;
  const int l15 = lane & 15, lhi = lane >> 4;
  const int m0 = blockIdx.y * 128, n0 = blockIdx.x * 128;

  f32x4 acc[4][4] = {};
#pragma unroll 1
  for (int kt = 0; kt < 24; ++kt) {
    const int k0 = kt * 64;
    stage32(As + wid * (32 * 64), A  + (size_t)(m0 + wid * 32) * 1536 + k0, 1536, lane);
    stage32(Bs + wid * (32 * 64), Bt + (size_t)(n0 + wid * 32) * 1536 + k0, 1536, lane);
    asm volatile("s_waitcnt vmcnt(0)" ::: "memory");
    __syncthreads();
#pragma unroll
    for (int kh = 0; kh < 2; ++kh) {
      bf16x8 af[4], bfv[4];
#pragma unroll
      for (int mt = 0; mt < 4; ++mt) af[mt]  = ldsFrag(As, wr * 64 + mt * 16 + l15, kh, lhi);
#pragma unroll
      for (int nt = 0; nt < 4; ++nt) bfv[nt] = ldsFrag(Bs, wc * 64 + nt * 16 + l15, kh, lhi);
#pragma unroll
      for (int mt = 0; mt < 4; ++mt)
#pragma unroll
        for (int nt = 0; nt < 4; ++nt)
          acc[mt][nt] = __builtin_amdgcn_mfma_f32_16x16x32_bf16(af[mt], bfv[nt], acc[mt][nt], 0, 0, 0);
    }
    __syncthreads();
  }
#pragma unroll
  for (int mt = 0; mt < 4; ++mt)
#pragma unroll
    for (int nt = 0; nt < 4; ++nt) {
      const int gn = n0 + wc * 64 + nt * 16 + l15;
      const float bs = bias[gn];
#pragma unroll
      for (int r = 0; r < 4; ++r) {
        const int gm = m0 + wr * 64 + mt * 16 + lhi * 4 + r;
        float v = acc[mt][nt][r] + bs;
        if (MODE == 0) {
          if (gn < Hc) v *= INV_SCALE;
          outb[(size_t)gm * ldo + gn] = f2bf(v);
        } else {
          v += resid[(size_t)gm * ldo + gn];
          outf[(size_t)gm * ldo + gn] = v;
        }
      }
    }
}

// ---------------- prep: bias concat, valid vector, single delta->index table ----------------
// T[d] = clip(bucket(d)+256): covers both c2p (q-k) and p2c (odd symmetry + swapaxes).
__global__ __launch_bounds__(256) void prep_misc(
    const float* __restrict__ bq, const float* __restrict__ bk, const float* __restrict__ bv,
    const int* __restrict__ am, const int* __restrict__ rp,
    float* __restrict__ bias, int* __restrict__ valid, u16* __restrict__ tbl)
{
  const int TOT = N3 + MX + 2047;
  for (int i = blockIdx.x * 256 + threadIdx.x; i < TOT; i += gridDim.x * 256) {
    if (i < N3) {
      bias[i] = i < Hc ? bq[i] : (i < 2 * Hc ? bk[i - Hc] : bv[i - 2 * Hc]);
    } else if (i < N3 + MX) {
      const int j = i - N3, b = j >> 10, s = j & 1023;
      valid[j] = am[(size_t)b * Sc * Sc + (size_t)s * Sc + s];
    } else {
      const int t = i - (N3 + MX), d = t - 1023;                 // delta = q - k
      int v = (d >= 0 ? rp[(size_t)d * Sc] : rp[-d]) + 256;      // clip(bucket(d)+256)
      v = v < 0 ? 0 : (v > 511 ? 511 : v);
      tbl[t] = (u16)v;
    }
  }
}

// ---------------- lens: per-batch valid length (prefix property) ----------------
__global__ void len_kernel(const int* __restrict__ valid, int* __restrict__ LENS)
{
  const int tid = threadIdx.x, wid = tid >> 6, lane = tid & 63;   // wid = b
  int s = 0;
#pragma unroll
  for (int j = 0; j < 16; ++j) s += valid[wid * Sc + j * 64 + lane];
#pragma unroll
  for (int off = 1; off <= 32; off <<= 1) s += __shfl_xor(s, off);
  if (lane == 0) LENS[wid] = s;
}

// ---------------- cast [X ; rel_emb] -> bf16 A-matrix ----------------
__global__ __launch_bounds__(256) void cast_x(const float* __restrict__ hs,
                                              const float* __restrict__ rel,
                                              u16* __restrict__ A)
{
  const size_t total = (size_t)MA * Hc / 4;
  for (size_t i = (size_t)blockIdx.x * 256 + threadIdx.x; i < total; i += (size_t)gridDim.x * 256) {
    const size_t e = i * 4;
    const int row = (int)(e / Hc), col = (int)(e % Hc);
    const float* s = row < MX ? hs + (size_t)row * Hc + col : rel + (size_t)(row - MX) * Hc + col;
    f32x4 v = *(const f32x4*)s;
    u16x4 o = { f2bf(v[0]), f2bf(v[1]), f2bf(v[2]), f2bf(v[3]) };
    *(u16x4*)(A + e) = o;
  }
}

// ---------------- transpose-cast weights ----------------
__global__ void transpose_cast(const float* __restrict__ Wq, const float* __restrict__ Wk,
                               const float* __restrict__ Wv, const float* __restrict__ Wo,
                               u16* __restrict__ WT, u16* __restrict__ WOT)
{
  const int z = blockIdx.z;
  const float* src = z == 0 ? Wq : z == 1 ? Wk : z == 2 ? Wv : Wo;
  u16* dst = z == 3 ? WOT : WT + (size_t)z * Hc * Hc;
  __shared__ float t[32][33];
  const int tx = threadIdx.x, ty = threadIdx.y;
  const int kb = blockIdx.y * 32, nb = blockIdx.x * 32;
#pragma unroll
  for (int i = 0; i < 4; ++i)
    t[ty + i * 8][tx] = src[(size_t)(kb + ty + i * 8) * Hc + nb + tx];
  __syncthreads();
#pragma unroll
  for (int i = 0; i < 4; ++i)
    dst[(size_t)(nb + ty + i * 8) * Hc + kb + tx] = f2bf(t[tx][ty + i * 8]);
}

// ---------------- relmat4: LDS-staged B-panel, 8 blocks per bh ----------------
// v<4 : c2p[q][p]  tile m0=v*256      (M=1024, N=512), A=Qs rows,   B=PosK rows
// v>=4: p2cT[cc][k] tile m0,(n-half)  (M=512, N=1024), A=PosQs rows, B=K rows
// B-panel (512 rows x 64 cols, 64KB) staged once per block via global_load_lds.
__global__ __launch_bounds__(256) void relmat4(const u16* __restrict__ QKVP,
    u16* __restrict__ c2p, u16* __restrict__ p2cT, int bh_base)
{
  const int lbh = blockIdx.x >> 3, v = blockIdx.x & 7;
  const int bh = bh_base + lbh, b = bh / NHc, h = bh % NHc;
  const int tid = threadIdx.x, wid = tid >> 6, lane = tid & 63;
  const int l15 = lane & 15, lhi = lane >> 4, lhi4 = lhi * 4;

  __shared__ alignas(16) u16 Bs[512 * 64];   // 64 KB

  int m0, n0, ldo;
  size_t arow, brow;
  u16* out;
  if (v < 4) {
    m0 = v * 256; n0 = 0; ldo = P2c;
    arow = (size_t)b * Sc + m0; brow = (size_t)MX;
    out = c2p + (size_t)lbh * Sc * P2c;
  } else {
    m0 = ((v - 4) >> 1) * 256; n0 = ((v - 4) & 1) * 512; ldo = Sc;
    arow = (size_t)MX + m0; brow = (size_t)b * Sc + n0;
    out = p2cT + (size_t)lbh * P2c * Sc;
  }
  const int acol = h * 64;            // Qs / PosQs (scaled Q-projection block)
  const int bcol = Hc + h * 64;       // PosK / K   (K-projection block)

  // ---- stage B panel: 512 rows x 64 cols, XOR-swizzled ----
  const int srow = tid >> 3;                   // 0..31
  const int gsl  = (tid & 7) ^ (srow & 7);     // pre-swizzled source slot
#pragma unroll
  for (int it = 0; it < 16; ++it) {
    const int row = it * 32 + srow;
    const u16* gp = QKVP + (brow + row) * 4608 + bcol + gsl * 8;
#if HAVE_GLL
    __builtin_amdgcn_global_load_lds(
        (const __attribute__((address_space(1))) void*)gp,
        (__attribute__((address_space(3))) void*)(&Bs[it * 2048 + wid * 512]),
        16, 0, 0);
#else
    *(i32x4*)(&Bs[row * 64 + (tid & 7) * 8]) = *(const i32x4*)gp;
#endif
  }

  // ---- A frags: 64 rows per wave, direct from global (L2-hot) ----
  bf16x8 af[4][2];
#pragma unroll
  for (int mt = 0; mt < 4; ++mt)
#pragma unroll
    for (int kh = 0; kh < 2; ++kh)
      af[mt][kh] = *(const bf16x8*)(QKVP + (arow + wid * 64 + mt * 16 + l15) * 4608
                                    + acol + kh * 32 + lhi * 8);

  asm volatile("s_waitcnt vmcnt(0)" ::: "memory");
  __syncthreads();

  // ---- sweep N: 32 x 16-col frags; K=64 fully in registers ----
#pragma unroll 4
  for (int nt = 0; nt < 32; ++nt) {
    bf16x8 b0 = ldsFrag(Bs, nt * 16 + l15, 0, lhi);
    bf16x8 b1 = ldsFrag(Bs, nt * 16 + l15, 1, lhi);
    f32x4 acc[4] = {};
#pragma unroll
    for (int mt = 0; mt < 4; ++mt) {
      acc[mt] = __builtin_amdgcn_mfma_f32_16x16x32_bf16(af[mt][0], b0, acc[mt], 0, 0, 0);
      acc[mt] = __builtin_amdgcn_mfma_f32_16x16x32_bf16(af[mt][1], b1, acc[mt], 0, 0, 0);
    }
#pragma unroll
    for (int mt = 0; mt < 4; ++mt)
#pragma unroll
      for (int r = 0; r < 4; ++r) {
        const int mm = m0 + wid * 64 + mt * 16 + lhi4 + r;
        const int nn = n0 + nt * 16 + l15;
        out[(size_t)mm * ldo + nn] = f2bf(acc[mt][r]);
      }
  }
}

// ---------------- flash v4: LDS K/V, direct dual-gather (proven 110us) ----------------
DEV int svz(int d) { return ((d ^ (d >> 3)) & 7) << 3; }   // V swizzle: 2-way both sides

__global__ __launch_bounds__(256) void flash4(
    const u16* __restrict__ QKVP, const u16* __restrict__ c2p, const u16* __restrict__ p2cT,
    const int* __restrict__ LENS, const u16* __restrict__ tblG,
    u16* __restrict__ ctx, int bh_base, int chunkC)
{
  int id = blockIdx.x;
  const int grid = chunkC * 16;
  if ((grid & 7) == 0) {                    // bijective XCD swizzle: bh-contiguous per XCD
    const int cpx = grid >> 3;
    id = (id & 7) * cpx + (id >> 3);
  }
  const int lbh = id >> 4, qi = id & 15;
  const int bh = bh_base + lbh, b = bh / NHc, h = bh % NHc;
  const int tid = threadIdx.x, wid = tid >> 6, lane = tid & 63;
  const int l15 = lane & 15, lhi = lane >> 4, lhi4 = lhi * 4;
  const int qrb = qi * 64 + wid * 16;
  const int len = LENS[b], nkt = (len + 63) >> 6;

  __shared__ u16 Tt[2048];
  __shared__ alignas(16) u16 Kt[64 * 64];
  __shared__ alignas(16) u16 Vt[64 * 64];
  __shared__ alignas(16) u16 Pl[4][16 * 64];

  for (int i = tid; i < 2047; i += 256) Tt[i] = tblG[i];

  bf16x8 aq[2];
#pragma unroll
  for (int kh = 0; kh < 2; ++kh)
    aq[kh] = *(const bf16x8*)(QKVP + (size_t)(b * Sc + qrb + l15) * 4608 + h * 64 + kh * 32 + lhi * 8);

  const int kr = tid >> 2, dc = (tid & 3) * 16;
  const int sk = (kr & 7) * 8;
  const u16* Kg = QKVP + (size_t)b * Sc * 4608 + Hc + h * 64;
  const u16* Vg = QKVP + (size_t)b * Sc * 4608 + 2 * Hc + h * 64;

  auto writeKV = [&](u16x8 ka, u16x8 kb, u16x8 va, u16x8 vb) {
    *(u16x8*)(Kt + kr * 64 + (dc ^ sk))       = ka;
    *(u16x8*)(Kt + kr * 64 + ((dc ^ sk) ^ 8)) = kb;
#pragma unroll
    for (int i = 0; i < 8; ++i) { const int d = dc + i;     Vt[d * 64 + (kr ^ svz(d))] = va[i]; }
#pragma unroll
    for (int i = 0; i < 8; ++i) { const int d = dc + 8 + i; Vt[d * 64 + (kr ^ svz(d))] = vb[i]; }
  };

  { // prologue: tile 0
    const size_t ro = (size_t)kr * 4608 + dc;
    u16x8 ka = *(const u16x8*)(Kg + ro), kb = *(const u16x8*)(Kg + ro + 8);
    u16x8 va = *(const u16x8*)(Vg + ro), vb = *(const u16x8*)(Vg + ro + 8);
    writeKV(ka, kb, va, vb);
  }
  __syncthreads();                          // Tt + tile 0 visible

  const u16* c2pB  = c2p  + (size_t)lbh * Sc * P2c;
  const u16* p2cTB = p2cT + (size_t)lbh * P2c * Sc;
  u16* myP = Pl[wid];
  f32x4 o_acc[4] = {};
  float m_arr[4], l_arr[4];
#pragma unroll
  for (int r = 0; r < 4; ++r) { m_arr[r] = -1e30f; l_arr[r] = 0.f; }

  for (int kt = 0; kt < nkt; ++kt) {
    const int k0 = kt * 64;
    const bool more = (kt + 1 < nkt);
    u16x8 nka, nkb, nva, nvb;
    if (more) {                              // T14: issue next-tile loads early
      const size_t ro = (size_t)(k0 + 64 + kr) * 4608 + dc;
      nka = *(const u16x8*)(Kg + ro); nkb = *(const u16x8*)(Kg + ro + 8);
      nva = *(const u16x8*)(Vg + ro); nvb = *(const u16x8*)(Vg + ro + 8);
    }

    // dual gathers: c2p (q-row window) + p2cT (cc-row, k coalesced); issue before MFMA
    float relv[4][4];
#pragma unroll
    for (int j = 0; j < 4; ++j)
#pragma unroll
      for (int r = 0; r < 4; ++r) {
        const int q = qrb + lhi4 + r;
        const int k = k0 + j * 16 + l15;
        const int cc = Tt[q - k + 1023];
        relv[j][r] = bf2f(c2pB[(size_t)q * P2c + cc]) + bf2f(p2cTB[(size_t)cc * Sc + k]);
      }

    // S = Q K^T from LDS (rows q, cols k)
    f32x4 s[4];
    __builtin_amdgcn_s_setprio(1);
#pragma unroll
    for (int j = 0; j < 4; ++j) {
      f32x4 sv = {};
#pragma unroll
      for (int kh = 0; kh < 2; ++kh) {
        bf16x8 bk = ldsFrag(Kt, j * 16 + l15, kh, lhi);
        sv = __builtin_amdgcn_mfma_f32_16x16x32_bf16(aq[kh], bk, sv, 0, 0, 0);
      }
      s[j] = sv;
    }
    __builtin_amdgcn_s_setprio(0);

    float p[4][4];
#pragma unroll
    for (int j = 0; j < 4; ++j) {
      const bool kv = (k0 + j * 16 + l15) < len;
#pragma unroll
      for (int r = 0; r < 4; ++r)
        p[j][r] = kv ? (s[j][r] + relv[j][r]) : -1e30f;
    }

    float resc[4];
#pragma unroll
    for (int r = 0; r < 4; ++r) {
      float mx = fmaxf(fmaxf(p[0][r], p[1][r]), fmaxf(p[2][r], p[3][r]));
#pragma unroll
      for (int off = 1; off <= 8; off <<= 1) mx = fmaxf(mx, __shfl_xor(mx, off));
      const float mnew = fmaxf(m_arr[r], mx);
      const float sc = __expf(m_arr[r] - mnew);
      float rs = 0.f;
#pragma unroll
      for (int j = 0; j < 4; ++j) { p[j][r] = __expf(p[j][r] - mnew); rs += p[j][r]; }
#pragma unroll
      for (int off = 1; off <= 8; off <<= 1) rs += __shfl_xor(rs, off);
      l_arr[r] = l_arr[r] * sc + rs;
      m_arr[r] = mnew;
      resc[r] = sc;
    }
#pragma unroll
    for (int jd = 0; jd < 4; ++jd)
#pragma unroll
      for (int r = 0; r < 4; ++r) o_acc[jd][r] *= resc[r];

    // P strip (scalar LDS writes, row-XOR swizzle)
#pragma unroll
    for (int j = 0; j < 4; ++j)
#pragma unroll
      for (int r = 0; r < 4; ++r) {
        const int row = lhi4 + r, col = j * 16 + l15;
        myP[row * 64 + (col ^ ((row & 7) * 8))] = f2bf(p[j][r]);
      }

    // PV: O[q][d] += P[q][k] V[k][d]
    __builtin_amdgcn_s_setprio(1);
#pragma unroll
    for (int kh = 0; kh < 2; ++kh) {
      bf16x8 pa = *(const bf16x8*)(myP + l15 * 64 + ((kh * 32 + lhi * 8) ^ ((l15 & 7) * 8)));
#pragma unroll
      for (int jd = 0; jd < 4; ++jd) {
        const int d = jd * 16 + l15;
        bf16x8 vf = *(const bf16x8*)(Vt + d * 64 + ((kh * 32 + lhi * 8) ^ svz(d)));
        o_acc[jd] = __builtin_amdgcn_mfma_f32_16x16x32_bf16(pa, vf, o_acc[jd], 0, 0, 0);
      }
    }
    __builtin_amdgcn_s_setprio(0);

    __syncthreads();                      // all waves done reading Kt/Vt
    if (more) writeKV(nka, nkb, nva, nvb);
    __syncthreads();                      // next tile visible
  }

  // epilogue
#pragma unroll
  for (int r = 0; r < 4; ++r) {
    const int q = qrb + lhi4 + r;
    const float inv = (q < len && l_arr[r] > 0.f) ? 1.f / l_arr[r] : 0.f;
#pragma unroll
    for (int jd = 0; jd < 4; ++jd)
      ctx[(size_t)(b * Sc + q) * Hc + h * 64 + jd * 16 + l15] = f2bf(o_acc[jd][r] * inv);
  }
}

// ---------------- row-wise LayerNorm in-place on d_out ----------------
__global__ __launch_bounds__(256) void ln_kernel(float* __restrict__ io,
    const float* __restrict__ g, const float* __restrict__ bta)
{
  const int row = blockIdx.x;
  float* p = io + (size_t)row * Hc;
  const int tid = threadIdx.x, wid = tid >> 6, lane = tid & 63;
  float v[6];
  float s = 0.f;
#pragma unroll
  for (int j = 0; j < 6; ++j) { v[j] = p[tid + j * 256]; s += v[j]; }
#pragma unroll
  for (int off = 1; off <= 32; off <<= 1) s += __shfl_xor(s, off);
  __shared__ float red[4];
  if (lane == 0) red[wid] = s;
  __syncthreads();
  const float mu = (red[0] + red[1] + red[2] + red[3]) * (1.f / Hc);
  float q = 0.f;
#pragma unroll
  for (int j = 0; j < 6; ++j) { const float d = v[j] - mu; q += d * d; }
#pragma unroll
  for (int off = 1; off <= 32; off <<= 1) q += __shfl_xor(q, off);
  __syncthreads();
  if (lane == 0) red[wid] = q;
  __syncthreads();
  const float rstd = rsqrtf((red[0] + red[1] + red[2] + red[3]) * (1.f / Hc) + 1e-7f);
#pragma unroll
  for (int j = 0; j < 6; ++j) {
    const int c = tid + j * 256;
    p[c] = (v[j] - mu) * rstd * g[c] + bta[c];
  }
}

// ---------------- host launcher ----------------
extern "C" void kernel_launch(void* const* d_in, const int* in_sizes, int n_in,
                              void* d_out, int out_size, void* d_ws, size_t ws_size,
                              hipStream_t stream)
{
  (void)in_sizes; (void)n_in; (void)out_size;
  const float* hidden = (const float*)d_in[0];
  const float* relemb = (const float*)d_in[1];
  const float* Wq = (const float*)d_in[2];
  const float* bq = (const float*)d_in[3];
  const float* Wk = (const float*)d_in[4];
  const float* bk = (const float*)d_in[5];
  const float* Wv = (const float*)d_in[6];
  const float* bv = (const float*)d_in[7];
  const float* Wo = (const float*)d_in[8];
  const float* bo = (const float*)d_in[9];
  const float* lng = (const float*)d_in[10];
  const float* lnb = (const float*)d_in[11];
  const int* am = (const int*)d_in[12];
  const int* rp = (const int*)d_in[13];
  float* out = (float*)d_out;

  char* ws = (char*)d_ws;
  size_t off = 0;
  auto alloc = [&](size_t bytes) { size_t r = off; off += (bytes + 255) & ~(size_t)255; return r; };
  const size_t o_qkvp = alloc((size_t)MA * 4608 * 2);
  const size_t o_wt   = alloc((size_t)N3 * Hc * 2);
  const size_t o_wot  = alloc((size_t)Hc * Hc * 2);
  const size_t o_abig = alloc((size_t)MA * Hc * 2);
  const size_t o_bias = alloc((size_t)N3 * 4);
  const size_t o_valid= alloc((size_t)MX * 4);
  const size_t o_tbl  = alloc(2048 * 2);
  const size_t o_lens = alloc(256);
  const size_t fixed  = off;
  const size_t o_rel  = off;

  const size_t perbh = (size_t)Sc * P2c * 2 * 2;   // c2p + p2cT = 2MB per bh
  int c = 96;
  while (c > 1 && fixed + (size_t)c * perbh > ws_size) c >>= 1;

  u16* QKVP = (u16*)(ws + o_qkvp);
  u16* WT   = (u16*)(ws + o_wt);
  u16* WOT  = (u16*)(ws + o_wot);
  u16* ABIG = (u16*)(ws + o_abig);
  u16* CTX  = (u16*)(ws + o_abig);                      // alias: ABIG dead after gemm<0>
  float* BIAS = (float*)(ws + o_bias);
  int* VALID  = (int*)(ws + o_valid);
  u16* TBL  = (u16*)(ws + o_tbl);
  int* LENS = (int*)(ws + o_lens);
  u16* C2P  = (u16*)(ws + o_rel);
  u16* P2CT = C2P + (size_t)c * Sc * P2c;

  prep_misc<<<dim3(50), dim3(256), 0, stream>>>(bq, bk, bv, am, rp, BIAS, VALID, TBL);
  len_kernel<<<dim3(1), dim3(256), 0, stream>>>(VALID, LENS);
  cast_x<<<dim3(1728), dim3(256), 0, stream>>>(hidden, relemb, ABIG);
  transpose_cast<<<dim3(48, 48, 4), dim3(32, 8), 0, stream>>>(Wq, Wk, Wv, Wo, WT, WOT);
  gemm128<0><<<dim3(36, 36), dim3(256), 0, stream>>>(ABIG, WT, BIAS, (const float*)nullptr,
                                                     QKVP, (float*)nullptr, 4608);
  for (int base = 0; base < 96; base += c) {
    relmat4<<<dim3(8 * c), dim3(256), 0, stream>>>(QKVP, C2P, P2CT, base);
    flash4<<<dim3(c * 16), dim3(256), 0, stream>>>(QKVP, C2P, P2CT, LENS, TBL, CTX, base, c);
  }
  gemm128<1><<<dim3(12, 32), dim3(256), 0, stream>>>(CTX, WOT, bo, hidden,
                                                     (u16*)nullptr, out, Hc);
  ln_kernel<<<dim3(MX), dim3(256), 0, stream>>>(out, lng, lnb);
}

// Round 7
// 400.801 us; speedup vs baseline: 1.2261x; 1.0184x over previous
//
#include <hip/hip_runtime.h>
#include <hip/hip_bf16.h>

// ---------------- problem constants ----------------
constexpr int Bc  = 4;
constexpr int Sc  = 1024;
constexpr int Hc  = 1536;
constexpr int NHc = 24;
constexpr int P2c = 512;            // 2*ATT_SPAN
constexpr int MX  = Bc * Sc;        // 4096 rows of X
constexpr int MA  = MX + P2c;       // 4608 rows of [X ; rel_emb]
constexpr int N3  = 3 * Hc;         // 4608 output cols (q|k|v)
constexpr float INV_SCALE = 0.07216878364870323f;  // 1/sqrt(64*3)

using f32x4  = __attribute__((ext_vector_type(4))) float;
using bf16x8 = __attribute__((ext_vector_type(8))) short;
using i32x4  = __attribute__((ext_vector_type(4))) int;
using u16x8  = __attribute__((ext_vector_type(8))) unsigned short;
using u16x4  = __attribute__((ext_vector_type(4))) unsigned short;
typedef unsigned short u16;

#define DEV __device__ __forceinline__

DEV float bf2f(u16 u) { return __uint_as_float(((unsigned)u) << 16); }
DEV u16   f2bf(float f) { return __builtin_bit_cast(unsigned short, __float2bfloat16(f)); }

#if defined(__has_builtin)
#if __has_builtin(__builtin_amdgcn_global_load_lds)
#define HAVE_GLL 1
#endif
#endif
#ifndef HAVE_GLL
#define HAVE_GLL 0
#endif

// Stage 32 rows x 64 bf16 cols of a row-major (stride ldk) global tile into LDS.
DEV void stage32(u16* lds, const u16* g, int ldk, int lane) {
#pragma unroll
  for (int c = 0; c < 4; ++c) {
    const int row   = c * 8 + (lane >> 3);
    const int gslot = (lane & 7) ^ (row & 7);          // pre-swizzled source (rule 21)
    const u16* gp = g + (size_t)row * ldk + gslot * 8;
#if HAVE_GLL
    __builtin_amdgcn_global_load_lds(
        (const __attribute__((address_space(1))) void*)gp,
        (__attribute__((address_space(3))) void*)(lds + c * 8 * 64),
        16, 0, 0);
#else
    i32x4 v = *(const i32x4*)gp;
    *(i32x4*)(lds + row * 64 + (lane & 7) * 8) = v;
#endif
  }
}

DEV bf16x8 ldsFrag(const u16* base, int row, int kh, int lhi) {
  const int idx = row * 64 + ((kh * 32 + lhi * 8) ^ ((row & 7) * 8));
  return *(const bf16x8*)(base + idx);
}

// ---------------- GEMM: C[M,N] = A[M,K=1536] @ Bt[N,K]^T  (+ epilogue) ----------------
// MODE 0: out = bf16((acc + bias[n]) * (n<1536 ? 1/sqrt(192) : 1))   (QKV+pos proj)
// MODE 1: out = f32(acc + bias[n] + resid[m,n])                       (out proj + residual)
template <int MODE>
__global__ __launch_bounds__(256) void gemm128(
    const u16* __restrict__ A, const u16* __restrict__ Bt,
    const float* __restrict__ bias, const float* __restrict__ resid,
    u16* __restrict__ outb, float* __restrict__ outf, int ldo)
{
  __shared__ alignas(16) u16 As[128 * 64];
  __shared__ alignas(16) u16 Bs[128 * 64];
  const int tid = threadIdx.x, wid = tid >> 6, lane = tid & 63;
  const int wr = wid >> 1, wc = wid & 1;
  const int l15 = lane & 15, lhi = lane >> 4;
  const int m0 = blockIdx.y * 128, n0 = blockIdx.x * 128;

  f32x4 acc[4][4] = {};
#pragma unroll 1
  for (int kt = 0; kt < 24; ++kt) {
    const int k0 = kt * 64;
    stage32(As + wid * (32 * 64), A  + (size_t)(m0 + wid * 32) * 1536 + k0, 1536, lane);
    stage32(Bs + wid * (32 * 64), Bt + (size_t)(n0 + wid * 32) * 1536 + k0, 1536, lane);
    asm volatile("s_waitcnt vmcnt(0)" ::: "memory");
    __syncthreads();
#pragma unroll
    for (int kh = 0; kh < 2; ++kh) {
      bf16x8 af[4], bfv[4];
#pragma unroll
      for (int mt = 0; mt < 4; ++mt) af[mt]  = ldsFrag(As, wr * 64 + mt * 16 + l15, kh, lhi);
#pragma unroll
      for (int nt = 0; nt < 4; ++nt) bfv[nt] = ldsFrag(Bs, wc * 64 + nt * 16 + l15, kh, lhi);
#pragma unroll
      for (int mt = 0; mt < 4; ++mt)
#pragma unroll
        for (int nt = 0; nt < 4; ++nt)
          acc[mt][nt] = __builtin_amdgcn_mfma_f32_16x16x32_bf16(af[mt], bfv[nt], acc[mt][nt], 0, 0, 0);
    }
    __syncthreads();
  }
#pragma unroll
  for (int mt = 0; mt < 4; ++mt)
#pragma unroll
    for (int nt = 0; nt < 4; ++nt) {
      const int gn = n0 + wc * 64 + nt * 16 + l15;
      const float bs = bias[gn];
#pragma unroll
      for (int r = 0; r < 4; ++r) {
        const int gm = m0 + wr * 64 + mt * 16 + lhi * 4 + r;
        float v = acc[mt][nt][r] + bs;
        if (MODE == 0) {
          if (gn < Hc) v *= INV_SCALE;
          outb[(size_t)gm * ldo + gn] = f2bf(v);
        } else {
          v += resid[(size_t)gm * ldo + gn];
          outf[(size_t)gm * ldo + gn] = v;
        }
      }
    }
}

// ---------------- prep: bias concat, valid vector, single delta->index table ----------------
// T[d] = clip(bucket(d)+256): covers both c2p (q-k) and p2c (odd symmetry + swapaxes).
__global__ __launch_bounds__(256) void prep_misc(
    const float* __restrict__ bq, const float* __restrict__ bk, const float* __restrict__ bv,
    const int* __restrict__ am, const int* __restrict__ rp,
    float* __restrict__ bias, int* __restrict__ valid, u16* __restrict__ tbl)
{
  const int TOT = N3 + MX + 2047;
  for (int i = blockIdx.x * 256 + threadIdx.x; i < TOT; i += gridDim.x * 256) {
    if (i < N3) {
      bias[i] = i < Hc ? bq[i] : (i < 2 * Hc ? bk[i - Hc] : bv[i - 2 * Hc]);
    } else if (i < N3 + MX) {
      const int j = i - N3, b = j >> 10, s = j & 1023;
      valid[j] = am[(size_t)b * Sc * Sc + (size_t)s * Sc + s];
    } else {
      const int t = i - (N3 + MX), d = t - 1023;                 // delta = q - k
      int v = (d >= 0 ? rp[(size_t)d * Sc] : rp[-d]) + 256;      // clip(bucket(d)+256)
      v = v < 0 ? 0 : (v > 511 ? 511 : v);
      tbl[t] = (u16)v;
    }
  }
}

// ---------------- lens: per-batch valid length (prefix property) ----------------
__global__ void len_kernel(const int* __restrict__ valid, int* __restrict__ LENS)
{
  const int tid = threadIdx.x, wid = tid >> 6, lane = tid & 63;   // wid = b
  int s = 0;
#pragma unroll
  for (int j = 0; j < 16; ++j) s += valid[wid * Sc + j * 64 + lane];
#pragma unroll
  for (int off = 1; off <= 32; off <<= 1) s += __shfl_xor(s, off);
  if (lane == 0) LENS[wid] = s;
}

// ---------------- cast [X ; rel_emb] -> bf16 A-matrix ----------------
__global__ __launch_bounds__(256) void cast_x(const float* __restrict__ hs,
                                              const float* __restrict__ rel,
                                              u16* __restrict__ A)
{
  const size_t total = (size_t)MA * Hc / 4;
  for (size_t i = (size_t)blockIdx.x * 256 + threadIdx.x; i < total; i += (size_t)gridDim.x * 256) {
    const size_t e = i * 4;
    const int row = (int)(e / Hc), col = (int)(e % Hc);
    const float* s = row < MX ? hs + (size_t)row * Hc + col : rel + (size_t)(row - MX) * Hc + col;
    f32x4 v = *(const f32x4*)s;
    u16x4 o = { f2bf(v[0]), f2bf(v[1]), f2bf(v[2]), f2bf(v[3]) };
    *(u16x4*)(A + e) = o;
  }
}

// ---------------- transpose-cast weights ----------------
__global__ void transpose_cast(const float* __restrict__ Wq, const float* __restrict__ Wk,
                               const float* __restrict__ Wv, const float* __restrict__ Wo,
                               u16* __restrict__ WT, u16* __restrict__ WOT)
{
  const int z = blockIdx.z;
  const float* src = z == 0 ? Wq : z == 1 ? Wk : z == 2 ? Wv : Wo;
  u16* dst = z == 3 ? WOT : WT + (size_t)z * Hc * Hc;
  __shared__ float t[32][33];
  const int tx = threadIdx.x, ty = threadIdx.y;
  const int kb = blockIdx.y * 32, nb = blockIdx.x * 32;
#pragma unroll
  for (int i = 0; i < 4; ++i)
    t[ty + i * 8][tx] = src[(size_t)(kb + ty + i * 8) * Hc + nb + tx];
  __syncthreads();
#pragma unroll
  for (int i = 0; i < 4; ++i)
    dst[(size_t)(nb + ty + i * 8) * Hc + kb + tx] = f2bf(t[tx][ty + i * 8]);
}

// ---------------- relmat4: LDS-staged B-panel, 8 blocks per bh ----------------
__global__ __launch_bounds__(256) void relmat4(const u16* __restrict__ QKVP,
    u16* __restrict__ c2p, u16* __restrict__ p2cT, int bh_base)
{
  const int lbh = blockIdx.x >> 3, v = blockIdx.x & 7;
  const int bh = bh_base + lbh, b = bh / NHc, h = bh % NHc;
  const int tid = threadIdx.x, wid = tid >> 6, lane = tid & 63;
  const int l15 = lane & 15, lhi = lane >> 4, lhi4 = lhi * 4;

  __shared__ alignas(16) u16 Bs[512 * 64];   // 64 KB

  int m0, n0, ldo;
  size_t arow, brow;
  u16* out;
  if (v < 4) {
    m0 = v * 256; n0 = 0; ldo = P2c;
    arow = (size_t)b * Sc + m0; brow = (size_t)MX;
    out = c2p + (size_t)lbh * Sc * P2c;
  } else {
    m0 = ((v - 4) >> 1) * 256; n0 = ((v - 4) & 1) * 512; ldo = Sc;
    arow = (size_t)MX + m0; brow = (size_t)b * Sc + n0;
    out = p2cT + (size_t)lbh * P2c * Sc;
  }
  const int acol = h * 64;            // Qs / PosQs (scaled Q-projection block)
  const int bcol = Hc + h * 64;       // PosK / K   (K-projection block)

  // ---- stage B panel: 512 rows x 64 cols, XOR-swizzled ----
  const int srow = tid >> 3;                   // 0..31
  const int gsl  = (tid & 7) ^ (srow & 7);     // pre-swizzled source slot
#pragma unroll
  for (int it = 0; it < 16; ++it) {
    const int row = it * 32 + srow;
    const u16* gp = QKVP + (brow + row) * 4608 + bcol + gsl * 8;
#if HAVE_GLL
    __builtin_amdgcn_global_load_lds(
        (const __attribute__((address_space(1))) void*)gp,
        (__attribute__((address_space(3))) void*)(&Bs[it * 2048 + wid * 512]),
        16, 0, 0);
#else
    *(i32x4*)(&Bs[row * 64 + (tid & 7) * 8]) = *(const i32x4*)gp;
#endif
  }

  // ---- A frags: 64 rows per wave, direct from global (L2-hot) ----
  bf16x8 af[4][2];
#pragma unroll
  for (int mt = 0; mt < 4; ++mt)
#pragma unroll
    for (int kh = 0; kh < 2; ++kh)
      af[mt][kh] = *(const bf16x8*)(QKVP + (arow + wid * 64 + mt * 16 + l15) * 4608
                                    + acol + kh * 32 + lhi * 8);

  asm volatile("s_waitcnt vmcnt(0)" ::: "memory");
  __syncthreads();

  // ---- sweep N: 32 x 16-col frags; K=64 fully in registers ----
#pragma unroll 4
  for (int nt = 0; nt < 32; ++nt) {
    bf16x8 b0 = ldsFrag(Bs, nt * 16 + l15, 0, lhi);
    bf16x8 b1 = ldsFrag(Bs, nt * 16 + l15, 1, lhi);
    f32x4 acc[4] = {};
#pragma unroll
    for (int mt = 0; mt < 4; ++mt) {
      acc[mt] = __builtin_amdgcn_mfma_f32_16x16x32_bf16(af[mt][0], b0, acc[mt], 0, 0, 0);
      acc[mt] = __builtin_amdgcn_mfma_f32_16x16x32_bf16(af[mt][1], b1, acc[mt], 0, 0, 0);
    }
#pragma unroll
    for (int mt = 0; mt < 4; ++mt)
#pragma unroll
      for (int r = 0; r < 4; ++r) {
        const int mm = m0 + wid * 64 + mt * 16 + lhi4 + r;
        const int nn = n0 + nt * 16 + l15;
        out[(size_t)mm * ldo + nn] = f2bf(acc[mt][r]);
      }
  }
}

// ---------------- flash v6: 8 waves / 128 q, dbuf K/V (1 barrier), exp-no-max softmax ----
// No-max softmax is exact here: |S| <= ~5 << 88 (f32 exp overflow), masked keys give
// exp(-1e30) = 0, and row sums accumulate in-lane with ONE cross-lane reduce at the end.
DEV int svz(int d) { return ((d ^ (d >> 3)) & 7) << 3; }   // V swizzle: 2-way both sides

__global__ __launch_bounds__(512) void flash6(
    const u16* __restrict__ QKVP, const u16* __restrict__ c2p, const u16* __restrict__ p2cT,
    const int* __restrict__ LENS, const u16* __restrict__ tblG,
    u16* __restrict__ ctx, int bh_base, int chunkC)
{
  int id = blockIdx.x;
  const int grid = chunkC * 8;
  if ((grid & 7) == 0) {                    // bijective XCD swizzle: bh-contiguous per XCD
    const int cpx = grid >> 3;
    id = (id & 7) * cpx + (id >> 3);
  }
  const int lbh = id >> 3, qi = id & 7;
  const int bh = bh_base + lbh, b = bh / NHc, h = bh % NHc;
  const int tid = threadIdx.x, wid = tid >> 6, lane = tid & 63;
  const int l15 = lane & 15, lhi = lane >> 4, lhi4 = lhi * 4;
  const int qrb = qi * 128 + wid * 16;
  const int len = LENS[b], nkt = (len + 63) >> 6;

  __shared__ u16 Tt[2048];
  __shared__ alignas(16) u16 Kt[2][64 * 64];
  __shared__ alignas(16) u16 Vt[2][64 * 64];
  __shared__ alignas(16) u16 Pl[8][16 * 64];

  for (int i = tid; i < 2047; i += 512) Tt[i] = tblG[i];

  bf16x8 aq[2];
#pragma unroll
  for (int kh = 0; kh < 2; ++kh)
    aq[kh] = *(const bf16x8*)(QKVP + (size_t)(b * Sc + qrb + l15) * 4608 + h * 64 + kh * 32 + lhi * 8);

  // staging: 512 threads cover 64 rows x 64 cols with one 16B chunk each
  const int kr = tid >> 3, dc8 = (tid & 7) * 8, kch = tid & 7;
  const u16* Kg = QKVP + (size_t)b * Sc * 4608 + Hc + h * 64;
  const u16* Vg = QKVP + (size_t)b * Sc * 4608 + 2 * Hc + h * 64;

  auto writeKV = [&](int buf, u16x8 kv, u16x8 vv) {
    *(u16x8*)(&Kt[buf][kr * 64 + ((kch ^ (kr & 7)) << 3)]) = kv;
#pragma unroll
    for (int i = 0; i < 8; ++i) { const int d = dc8 + i; Vt[buf][d * 64 + (kr ^ svz(d))] = vv[i]; }
  };

  { // prologue: tile 0
    const size_t ro = (size_t)kr * 4608 + dc8;
    u16x8 kv = *(const u16x8*)(Kg + ro);
    u16x8 vv = *(const u16x8*)(Vg + ro);
    writeKV(0, kv, vv);
  }
  __syncthreads();                          // Tt + tile 0 visible

  const u16* c2pB  = c2p  + (size_t)lbh * Sc * P2c;
  const u16* p2cTB = p2cT + (size_t)lbh * P2c * Sc;
  u16* myP = Pl[wid];
  f32x4 o_acc[4] = {};
  float lsum[4] = { 0.f, 0.f, 0.f, 0.f };
  int cur = 0;

  for (int kt = 0; kt < nkt; ++kt) {
    const int k0 = kt * 64;
    const bool more = (kt + 1 < nkt);
    u16x8 nk, nv;
    if (more) {                              // T14: issue next-tile loads early
      const size_t ro = (size_t)(k0 + 64 + kr) * 4608 + dc8;
      nk = *(const u16x8*)(Kg + ro);
      nv = *(const u16x8*)(Vg + ro);
    }

    // dual gathers: c2p (q-row window) + p2cT (cc-row, k coalesced far from diag)
    float relv[4][4];
#pragma unroll
    for (int j = 0; j < 4; ++j)
#pragma unroll
      for (int r = 0; r < 4; ++r) {
        const int q = qrb + lhi4 + r;
        const int k = k0 + j * 16 + l15;
        const int cc = Tt[q - k + 1023];
        relv[j][r] = bf2f(c2pB[(size_t)q * P2c + cc]) + bf2f(p2cTB[(size_t)cc * Sc + k]);
      }

    // S = Q K^T from LDS (rows q, cols k)
    f32x4 s[4];
    __builtin_amdgcn_s_setprio(1);
#pragma unroll
    for (int j = 0; j < 4; ++j) {
      f32x4 sv = {};
#pragma unroll
      for (int kh = 0; kh < 2; ++kh) {
        bf16x8 bk = ldsFrag(Kt[cur], j * 16 + l15, kh, lhi);
        sv = __builtin_amdgcn_mfma_f32_16x16x32_bf16(aq[kh], bk, sv, 0, 0, 0);
      }
      s[j] = sv;
    }
    __builtin_amdgcn_s_setprio(0);

    // exp (no max-sub), in-lane row-sum accumulation; masked keys -> 0
    float p[4][4];
#pragma unroll
    for (int j = 0; j < 4; ++j) {
      const bool kv = (k0 + j * 16 + l15) < len;
#pragma unroll
      for (int r = 0; r < 4; ++r)
        p[j][r] = kv ? __expf(s[j][r] + relv[j][r]) : 0.f;
    }
#pragma unroll
    for (int r = 0; r < 4; ++r)
      lsum[r] += (p[0][r] + p[1][r]) + (p[2][r] + p[3][r]);

    // P strip (scalar LDS writes, row-XOR swizzle)
#pragma unroll
    for (int j = 0; j < 4; ++j)
#pragma unroll
      for (int r = 0; r < 4; ++r) {
        const int row = lhi4 + r, col = j * 16 + l15;
        myP[row * 64 + (col ^ ((row & 7) * 8))] = f2bf(p[j][r]);
      }

    // PV: O[q][d] += P[q][k] V[k][d]
    __builtin_amdgcn_s_setprio(1);
#pragma unroll
    for (int kh = 0; kh < 2; ++kh) {
      bf16x8 pa = *(const bf16x8*)(myP + l15 * 64 + ((kh * 32 + lhi * 8) ^ ((l15 & 7) * 8)));
#pragma unroll
      for (int jd = 0; jd < 4; ++jd) {
        const int d = jd * 16 + l15;
        bf16x8 vf = *(const bf16x8*)(&Vt[cur][d * 64 + ((kh * 32 + lhi * 8) ^ svz(d))]);
        o_acc[jd] = __builtin_amdgcn_mfma_f32_16x16x32_bf16(pa, vf, o_acc[jd], 0, 0, 0);
      }
    }
    __builtin_amdgcn_s_setprio(0);

    // stage next tile into the OTHER buffer; one barrier bounds wave skew to <1 iter
    if (more) writeKV(cur ^ 1, nk, nv);
    __syncthreads();
    cur ^= 1;
  }

  // epilogue: one cross-lane sum reduce per row, then normalize + store
#pragma unroll
  for (int r = 0; r < 4; ++r) {
    float l = lsum[r];
#pragma unroll
    for (int off = 1; off <= 8; off <<= 1) l += __shfl_xor(l, off);
    const int q = qrb + lhi4 + r;
    const float inv = (q < len && l > 0.f) ? 1.f / l : 0.f;
#pragma unroll
    for (int jd = 0; jd < 4; ++jd)
      ctx[(size_t)(b * Sc + q) * Hc + h * 64 + jd * 16 + l15] = f2bf(o_acc[jd][r] * inv);
  }
}

// ---------------- row-wise LayerNorm in-place on d_out ----------------
__global__ __launch_bounds__(256) void ln_kernel(float* __restrict__ io,
    const float* __restrict__ g, const float* __restrict__ bta)
{
  const int row = blockIdx.x;
  float* p = io + (size_t)row * Hc;
  const int tid = threadIdx.x, wid = tid >> 6, lane = tid & 63;
  float v[6];
  float s = 0.f;
#pragma unroll
  for (int j = 0; j < 6; ++j) { v[j] = p[tid + j * 256]; s += v[j]; }
#pragma unroll
  for (int off = 1; off <= 32; off <<= 1) s += __shfl_xor(s, off);
  __shared__ float red[4];
  if (lane == 0) red[wid] = s;
  __syncthreads();
  const float mu = (red[0] + red[1] + red[2] + red[3]) * (1.f / Hc);
  float q = 0.f;
#pragma unroll
  for (int j = 0; j < 6; ++j) { const float d = v[j] - mu; q += d * d; }
#pragma unroll
  for (int off = 1; off <= 32; off <<= 1) q += __shfl_xor(q, off);
  __syncthreads();
  if (lane == 0) red[wid] = q;
  __syncthreads();
  const float rstd = rsqrtf((red[0] + red[1] + red[2] + red[3]) * (1.f / Hc) + 1e-7f);
#pragma unroll
  for (int j = 0; j < 6; ++j) {
    const int c = tid + j * 256;
    p[c] = (v[j] - mu) * rstd * g[c] + bta[c];
  }
}

// ---------------- host launcher ----------------
extern "C" void kernel_launch(void* const* d_in, const int* in_sizes, int n_in,
                              void* d_out, int out_size, void* d_ws, size_t ws_size,
                              hipStream_t stream)
{
  (void)in_sizes; (void)n_in; (void)out_size;
  const float* hidden = (const float*)d_in[0];
  const float* relemb = (const float*)d_in[1];
  const float* Wq = (const float*)d_in[2];
  const float* bq = (const float*)d_in[3];
  const float* Wk = (const float*)d_in[4];
  const float* bk = (const float*)d_in[5];
  const float* Wv = (const float*)d_in[6];
  const float* bv = (const float*)d_in[7];
  const float* Wo = (const float*)d_in[8];
  const float* bo = (const float*)d_in[9];
  const float* lng = (const float*)d_in[10];
  const float* lnb = (const float*)d_in[11];
  const int* am = (const int*)d_in[12];
  const int* rp = (const int*)d_in[13];
  float* out = (float*)d_out;

  char* ws = (char*)d_ws;
  size_t off = 0;
  auto alloc = [&](size_t bytes) { size_t r = off; off += (bytes + 255) & ~(size_t)255; return r; };
  const size_t o_qkvp = alloc((size_t)MA * 4608 * 2);
  const size_t o_wt   = alloc((size_t)N3 * Hc * 2);
  const size_t o_wot  = alloc((size_t)Hc * Hc * 2);
  const size_t o_abig = alloc((size_t)MA * Hc * 2);
  const size_t o_bias = alloc((size_t)N3 * 4);
  const size_t o_valid= alloc((size_t)MX * 4);
  const size_t o_tbl  = alloc(2048 * 2);
  const size_t o_lens = alloc(256);
  const size_t fixed  = off;
  const size_t o_rel  = off;

  const size_t perbh = (size_t)Sc * P2c * 2 * 2;   // c2p + p2cT = 2MB per bh
  int c = 96;
  while (c > 1 && fixed + (size_t)c * perbh > ws_size) c >>= 1;

  u16* QKVP = (u16*)(ws + o_qkvp);
  u16* WT   = (u16*)(ws + o_wt);
  u16* WOT  = (u16*)(ws + o_wot);
  u16* ABIG = (u16*)(ws + o_abig);
  u16* CTX  = (u16*)(ws + o_abig);                      // alias: ABIG dead after gemm<0>
  float* BIAS = (float*)(ws + o_bias);
  int* VALID  = (int*)(ws + o_valid);
  u16* TBL  = (u16*)(ws + o_tbl);
  int* LENS = (int*)(ws + o_lens);
  u16* C2P  = (u16*)(ws + o_rel);
  u16* P2CT = C2P + (size_t)c * Sc * P2c;

  prep_misc<<<dim3(50), dim3(256), 0, stream>>>(bq, bk, bv, am, rp, BIAS, VALID, TBL);
  len_kernel<<<dim3(1), dim3(256), 0, stream>>>(VALID, LENS);
  cast_x<<<dim3(1728), dim3(256), 0, stream>>>(hidden, relemb, ABIG);
  transpose_cast<<<dim3(48, 48, 4), dim3(32, 8), 0, stream>>>(Wq, Wk, Wv, Wo, WT, WOT);
  gemm128<0><<<dim3(36, 36), dim3(256), 0, stream>>>(ABIG, WT, BIAS, (const float*)nullptr,
                                                     QKVP, (float*)nullptr, 4608);
  for (int base = 0; base < 96; base += c) {
    relmat4<<<dim3(8 * c), dim3(256), 0, stream>>>(QKVP, C2P, P2CT, base);
    flash6<<<dim3(c * 8), dim3(512), 0, stream>>>(QKVP, C2P, P2CT, LENS, TBL, CTX, base, c);
  }
  gemm128<1><<<dim3(12, 32), dim3(256), 0, stream>>>(CTX, WOT, bo, hidden,
                                                     (u16*)nullptr, out, Hc);
  ln_kernel<<<dim3(MX), dim3(256), 0, stream>>>(out, lng, lnb);
}

// Round 8
// 385.730 us; speedup vs baseline: 1.2740x; 1.0391x over previous
//
#include <hip/hip_runtime.h>
#include <hip/hip_bf16.h>

// ---------------- problem constants ----------------
constexpr int Bc  = 4;
constexpr int Sc  = 1024;
constexpr int Hc  = 1536;
constexpr int NHc = 24;
constexpr int P2c = 512;            // 2*ATT_SPAN
constexpr int MX  = Bc * Sc;        // 4096 rows of X
constexpr int MA  = MX + P2c;       // 4608 rows of [X ; rel_emb]
constexpr int N3  = 3 * Hc;         // 4608 output cols (q|k|v)
constexpr float INV_SCALE = 0.07216878364870323f;  // 1/sqrt(64*3)

using f32x4  = __attribute__((ext_vector_type(4))) float;
using bf16x8 = __attribute__((ext_vector_type(8))) short;
using i32x4  = __attribute__((ext_vector_type(4))) int;
using u16x8  = __attribute__((ext_vector_type(8))) unsigned short;
using u16x4  = __attribute__((ext_vector_type(4))) unsigned short;
typedef unsigned short u16;

#define DEV __device__ __forceinline__

DEV float bf2f(u16 u) { return __uint_as_float(((unsigned)u) << 16); }
DEV u16   f2bf(float f) { return __builtin_bit_cast(unsigned short, __float2bfloat16(f)); }

#if defined(__has_builtin)
#if __has_builtin(__builtin_amdgcn_global_load_lds)
#define HAVE_GLL 1
#endif
#endif
#ifndef HAVE_GLL
#define HAVE_GLL 0
#endif

// LDS-only barrier: drain lgkmcnt but NOT vmcnt, so global prefetches stay in flight.
DEV void bar_lds() {
  asm volatile("s_waitcnt lgkmcnt(0)" ::: "memory");
  __builtin_amdgcn_s_barrier();
  asm volatile("" ::: "memory");
}

// Stage 32 rows x 64 bf16 cols of a row-major (stride ldk) global tile into LDS.
DEV void stage32(u16* lds, const u16* g, int ldk, int lane) {
#pragma unroll
  for (int c = 0; c < 4; ++c) {
    const int row   = c * 8 + (lane >> 3);
    const int gslot = (lane & 7) ^ (row & 7);          // pre-swizzled source (rule 21)
    const u16* gp = g + (size_t)row * ldk + gslot * 8;
#if HAVE_GLL
    __builtin_amdgcn_global_load_lds(
        (const __attribute__((address_space(1))) void*)gp,
        (__attribute__((address_space(3))) void*)(lds + c * 8 * 64),
        16, 0, 0);
#else
    i32x4 v = *(const i32x4*)gp;
    *(i32x4*)(lds + row * 64 + (lane & 7) * 8) = v;
#endif
  }
}

DEV bf16x8 ldsFrag(const u16* base, int row, int kh, int lhi) {
  const int idx = row * 64 + ((kh * 32 + lhi * 8) ^ ((row & 7) * 8));
  return *(const bf16x8*)(base + idx);
}

// ---------------- GEMM: C[M,N] = A[M,K=1536] @ Bt[N,K]^T  (+ epilogue) ----------------
template <int MODE>
__global__ __launch_bounds__(256) void gemm128(
    const u16* __restrict__ A, const u16* __restrict__ Bt,
    const float* __restrict__ bias, const float* __restrict__ resid,
    u16* __restrict__ outb, float* __restrict__ outf, int ldo)
{
  __shared__ alignas(16) u16 As[128 * 64];
  __shared__ alignas(16) u16 Bs[128 * 64];
  const int tid = threadIdx.x, wid = tid >> 6, lane = tid & 63;
  const int wr = wid >> 1, wc = wid & 1;
  const int l15 = lane & 15, lhi = lane >> 4;
  const int m0 = blockIdx.y * 128, n0 = blockIdx.x * 128;

  f32x4 acc[4][4] = {};
#pragma unroll 1
  for (int kt = 0; kt < 24; ++kt) {
    const int k0 = kt * 64;
    stage32(As + wid * (32 * 64), A  + (size_t)(m0 + wid * 32) * 1536 + k0, 1536, lane);
    stage32(Bs + wid * (32 * 64), Bt + (size_t)(n0 + wid * 32) * 1536 + k0, 1536, lane);
    asm volatile("s_waitcnt vmcnt(0)" ::: "memory");
    __syncthreads();
#pragma unroll
    for (int kh = 0; kh < 2; ++kh) {
      bf16x8 af[4], bfv[4];
#pragma unroll
      for (int mt = 0; mt < 4; ++mt) af[mt]  = ldsFrag(As, wr * 64 + mt * 16 + l15, kh, lhi);
#pragma unroll
      for (int nt = 0; nt < 4; ++nt) bfv[nt] = ldsFrag(Bs, wc * 64 + nt * 16 + l15, kh, lhi);
#pragma unroll
      for (int mt = 0; mt < 4; ++mt)
#pragma unroll
        for (int nt = 0; nt < 4; ++nt)
          acc[mt][nt] = __builtin_amdgcn_mfma_f32_16x16x32_bf16(af[mt], bfv[nt], acc[mt][nt], 0, 0, 0);
    }
    __syncthreads();
  }
#pragma unroll
  for (int mt = 0; mt < 4; ++mt)
#pragma unroll
    for (int nt = 0; nt < 4; ++nt) {
      const int gn = n0 + wc * 64 + nt * 16 + l15;
      const float bs = bias[gn];
#pragma unroll
      for (int r = 0; r < 4; ++r) {
        const int gm = m0 + wr * 64 + mt * 16 + lhi * 4 + r;
        float v = acc[mt][nt][r] + bs;
        if (MODE == 0) {
          if (gn < Hc) v *= INV_SCALE;
          outb[(size_t)gm * ldo + gn] = f2bf(v);
        } else {
          v += resid[(size_t)gm * ldo + gn];
          outf[(size_t)gm * ldo + gn] = v;
        }
      }
    }
}

// ---------------- prep: bias concat, valid vector, single delta->index table ----------------
__global__ __launch_bounds__(256) void prep_misc(
    const float* __restrict__ bq, const float* __restrict__ bk, const float* __restrict__ bv,
    const int* __restrict__ am, const int* __restrict__ rp,
    float* __restrict__ bias, int* __restrict__ valid, u16* __restrict__ tbl)
{
  const int TOT = N3 + MX + 2047;
  for (int i = blockIdx.x * 256 + threadIdx.x; i < TOT; i += gridDim.x * 256) {
    if (i < N3) {
      bias[i] = i < Hc ? bq[i] : (i < 2 * Hc ? bk[i - Hc] : bv[i - 2 * Hc]);
    } else if (i < N3 + MX) {
      const int j = i - N3, b = j >> 10, s = j & 1023;
      valid[j] = am[(size_t)b * Sc * Sc + (size_t)s * Sc + s];
    } else {
      const int t = i - (N3 + MX), d = t - 1023;                 // delta = q - k
      int v = (d >= 0 ? rp[(size_t)d * Sc] : rp[-d]) + 256;      // clip(bucket(d)+256)
      v = v < 0 ? 0 : (v > 511 ? 511 : v);
      tbl[t] = (u16)v;
    }
  }
}

// ---------------- lens: per-batch valid length (prefix property) ----------------
__global__ void len_kernel(const int* __restrict__ valid, int* __restrict__ LENS)
{
  const int tid = threadIdx.x, wid = tid >> 6, lane = tid & 63;   // wid = b
  int s = 0;
#pragma unroll
  for (int j = 0; j < 16; ++j) s += valid[wid * Sc + j * 64 + lane];
#pragma unroll
  for (int off = 1; off <= 32; off <<= 1) s += __shfl_xor(s, off);
  if (lane == 0) LENS[wid] = s;
}

// ---------------- cast [X ; rel_emb] -> bf16 A-matrix ----------------
__global__ __launch_bounds__(256) void cast_x(const float* __restrict__ hs,
                                              const float* __restrict__ rel,
                                              u16* __restrict__ A)
{
  const size_t total = (size_t)MA * Hc / 4;
  for (size_t i = (size_t)blockIdx.x * 256 + threadIdx.x; i < total; i += (size_t)gridDim.x * 256) {
    const size_t e = i * 4;
    const int row = (int)(e / Hc), col = (int)(e % Hc);
    const float* s = row < MX ? hs + (size_t)row * Hc + col : rel + (size_t)(row - MX) * Hc + col;
    f32x4 v = *(const f32x4*)s;
    u16x4 o = { f2bf(v[0]), f2bf(v[1]), f2bf(v[2]), f2bf(v[3]) };
    *(u16x4*)(A + e) = o;
  }
}

// ---------------- transpose-cast weights ----------------
__global__ void transpose_cast(const float* __restrict__ Wq, const float* __restrict__ Wk,
                               const float* __restrict__ Wv, const float* __restrict__ Wo,
                               u16* __restrict__ WT, u16* __restrict__ WOT)
{
  const int z = blockIdx.z;
  const float* src = z == 0 ? Wq : z == 1 ? Wk : z == 2 ? Wv : Wo;
  u16* dst = z == 3 ? WOT : WT + (size_t)z * Hc * Hc;
  __shared__ float t[32][33];
  const int tx = threadIdx.x, ty = threadIdx.y;
  const int kb = blockIdx.y * 32, nb = blockIdx.x * 32;
#pragma unroll
  for (int i = 0; i < 4; ++i)
    t[ty + i * 8][tx] = src[(size_t)(kb + ty + i * 8) * Hc + nb + tx];
  __syncthreads();
#pragma unroll
  for (int i = 0; i < 4; ++i)
    dst[(size_t)(nb + ty + i * 8) * Hc + kb + tx] = f2bf(t[tx][ty + i * 8]);
}

// ---------------- flash7: rel bias computed on the fly via MFMA, zero rel HBM traffic ----
// Per block: (bh, 64 q-rows). Phase A: c2pFull[64q][512cc] = Qs . PosK^T (PosK staged in LDS).
// Per k-tile: p2cW[64k][128w] = K_tile . PosQs_window^T (window exact: T is 1-Lipschitz,
// so cc-range over a 64x64 tile is <=127 wide). Gathers are LDS-only. Softmax = exp-no-max
// (proven round 6). 8 waves = 4 q-groups x 2 k-halves.
DEV int svz(int d) { return ((d ^ (d >> 3)) & 7) << 3; }

__global__ __launch_bounds__(512) void flash7(
    const u16* __restrict__ QKVP, const int* __restrict__ LENS,
    const u16* __restrict__ tblG, u16* __restrict__ ctx)
{
  int id = blockIdx.x;
  id = (id & 7) * 192 + (id >> 3);          // bijective XCD swizzle (1536 % 8 == 0)
  const int lbh = id >> 4, qt = id & 15;
  const int b = lbh / NHc, h = lbh % NHc;
  const int q0 = qt * 64;
  const int tid = threadIdx.x, wid = tid >> 6, lane = tid & 63;
  const int qg = wid & 3, half = wid >> 2;  // q-group, k-half
  const int l15 = lane & 15, lhi = lane >> 4, lhi4 = lhi * 4;
  const int qrb = q0 + qg * 16;
  const int len = LENS[b];

  if (q0 >= len) {                          // fully-masked q rows -> ctx = 0
    const int row = tid >> 3, c8 = (tid & 7) * 8;
    u16x8 z = {};
    *(u16x8*)(ctx + (size_t)(b * Sc + q0 + row) * Hc + h * 64 + c8) = z;
    return;
  }
  const int nkt = (len + 63) >> 6;

  __shared__ u16 Tt[2048];                       //  4 KB
  __shared__ alignas(16) u16 C2P_[64 * 514];     // 64.25 KB  c2pFull, pad 514
  __shared__ alignas(16) u16 R_[512 * 64];       // 64 KB: PosK (phase A) | PosQw+p2cW (loop)
  __shared__ alignas(16) u16 Kt[64 * 64];        //  8 KB
  __shared__ alignas(16) u16 Vt[64 * 64];        //  8 KB
  __shared__ alignas(16) u16 Pl[4][16 * 64];     //  8 KB (f32 scratch in epilogue)
  u16* PosQw = R_;                               // 128*64 u16
  u16* p2cW  = R_ + 128 * 64;                    // 64*130 u16 (pad 130)

  const u16* Qg = QKVP + (size_t)b * Sc * 4608 + h * 64;
  const u16* Kg = QKVP + (size_t)b * Sc * 4608 + Hc + h * 64;
  const u16* Vg = QKVP + (size_t)b * Sc * 4608 + 2 * Hc + h * 64;
  const u16* PosKg = QKVP + (size_t)MX * 4608 + Hc + h * 64;  // pos_k rows (K-proj)
  const u16* PosQg = QKVP + (size_t)MX * 4608 + h * 64;       // pos_q_s rows (scaled Q-proj)

  // ---------- prologue ----------
  for (int i = tid; i < 2047; i += 512) Tt[i] = tblG[i];

  bf16x8 aq[2];
#pragma unroll
  for (int kh = 0; kh < 2; ++kh)
    aq[kh] = *(const bf16x8*)(Qg + (size_t)(qrb + l15) * 4608 + kh * 32 + lhi * 8);

  // stage PosK full (512 rows x 64 cols) via gload_lds, XOR pre-swizzled source
#pragma unroll
  for (int it = 0; it < 8; ++it) {
    const int c = it * 512 + tid, row = c >> 3, slot = c & 7;
    const int gsl = slot ^ (row & 7);
    const u16* gp = PosKg + (size_t)row * 4608 + gsl * 8;
#if HAVE_GLL
    __builtin_amdgcn_global_load_lds(
        (const __attribute__((address_space(1))) void*)gp,
        (__attribute__((address_space(3))) void*)(R_ + (it * 512 + wid * 64) * 8),
        16, 0, 0);
#else
    *(i32x4*)(R_ + (size_t)row * 64 + (slot ^ (row & 7)) * 8) = *(const i32x4*)gp;
#endif
  }

  // K/V tile 0 reg loads
  const int kr = tid >> 3, ch = tid & 7;
  u16x8 kv0 = *(const u16x8*)(Kg + (size_t)kr * 4608 + ch * 8);
  u16x8 vv0 = *(const u16x8*)(Vg + (size_t)kr * 4608 + ch * 8);

  auto writeKV = [&](u16x8 kv, u16x8 vv) {
    *(u16x8*)(&Kt[kr * 64 + ((ch ^ (kr & 7)) << 3)]) = kv;
    const int dbase = ch * 8;
#pragma unroll
    for (int i = 0; i < 8; ++i) { const int d = dbase + i; Vt[d * 64 + (kr ^ svz(d))] = vv[i]; }
  };

  asm volatile("s_waitcnt vmcnt(0)" ::: "memory");
  __syncthreads();                           // Tt + PosK visible

  writeKV(kv0, vv0);                         // Kt/Vt tile 0

  // ---------- phase A: c2pFull = Qs . PosK^T ----------
#pragma unroll
  for (int nc = 0; nc < 2; ++nc) {
    f32x4 a8[8] = {};
#pragma unroll
    for (int kh = 0; kh < 2; ++kh)
#pragma unroll
      for (int u = 0; u < 8; ++u) {
        const int nt = half * 16 + nc * 8 + u;
        bf16x8 bfr = ldsFrag(R_, nt * 16 + l15, kh, lhi);
        a8[u] = __builtin_amdgcn_mfma_f32_16x16x32_bf16(aq[kh], bfr, a8[u], 0, 0, 0);
      }
#pragma unroll
    for (int u = 0; u < 8; ++u) {
      const int cc = (half * 16 + nc * 8 + u) * 16 + l15;
#pragma unroll
      for (int r = 0; r < 4; ++r)
        C2P_[(qg * 16 + lhi4 + r) * 514 + cc] = f2bf(a8[u][r]);
    }
  }
  bar_lds();                                 // c2pFull + Kt/Vt visible; PosK reads done

  // stage PosQw(0): window rows cc0(0)..cc0(0)+127
  int cc0 = min((int)Tt[q0 - 63 + 1023], P2c - 128);
  auto stagePosQ = [&](int base) {
#pragma unroll
    for (int it = 0; it < 2; ++it) {
      const int c = it * 512 + tid, row = c >> 3, slot = c & 7;
      const int gsl = slot ^ (row & 7);
      const u16* gp = PosQg + (size_t)(base + row) * 4608 + gsl * 8;
#if HAVE_GLL
      __builtin_amdgcn_global_load_lds(
          (const __attribute__((address_space(1))) void*)gp,
          (__attribute__((address_space(3))) void*)(PosQw + (it * 512 + wid * 64) * 8),
          16, 0, 0);
#else
      *(i32x4*)(PosQw + (size_t)row * 64 + (slot ^ (row & 7)) * 8) = *(const i32x4*)gp;
#endif
    }
  };
  stagePosQ(cc0);

  u16* myP = Pl[qg];
  f32x4 o_acc[2] = {};
  float lsum[4] = { 0.f, 0.f, 0.f, 0.f };

  // ---------- main loop over k-tiles ----------
  for (int kt = 0; kt < nkt; ++kt) {
    const int k0 = kt * 64;
    const bool more = (kt + 1 < nkt);

    asm volatile("s_waitcnt vmcnt(0)" ::: "memory");   // PosQw(kt) gloads done
    bar_lds();                                          // B1: PosQw + K/V(kt) visible

    // p2cW = K_tile . PosQw^T  (m-frag = qg, n-frags = half*4..half*4+3)
    {
      f32x4 a4[4] = {};
#pragma unroll
      for (int kh = 0; kh < 2; ++kh) {
        bf16x8 afr = ldsFrag(Kt, qg * 16 + l15, kh, lhi);
#pragma unroll
        for (int u = 0; u < 4; ++u) {
          const int nt = half * 4 + u;
          bf16x8 bfr = ldsFrag(PosQw, nt * 16 + l15, kh, lhi);
          a4[u] = __builtin_amdgcn_mfma_f32_16x16x32_bf16(afr, bfr, a4[u], 0, 0, 0);
        }
      }
#pragma unroll
      for (int u = 0; u < 4; ++u) {
        const int w = (half * 4 + u) * 16 + l15;
#pragma unroll
        for (int r = 0; r < 4; ++r)
          p2cW[(qg * 16 + lhi4 + r) * 130 + w] = f2bf(a4[u][r]);
      }
    }
    bar_lds();                                          // B2: p2cW visible

    // S = Q K^T (this wave's 2 k-subtiles)
    f32x4 s[2];
    __builtin_amdgcn_s_setprio(1);
#pragma unroll
    for (int jj = 0; jj < 2; ++jj) {
      f32x4 sv = {};
#pragma unroll
      for (int kh = 0; kh < 2; ++kh) {
        bf16x8 bk = ldsFrag(Kt, (half * 2 + jj) * 16 + l15, kh, lhi);
        sv = __builtin_amdgcn_mfma_f32_16x16x32_bf16(aq[kh], bk, sv, 0, 0, 0);
      }
      s[jj] = sv;
    }
    __builtin_amdgcn_s_setprio(0);

    // T14: issue next K/V tile loads
    u16x8 nk, nv;
    if (more) {
      nk = *(const u16x8*)(Kg + (size_t)(k0 + 64 + kr) * 4608 + ch * 8);
      nv = *(const u16x8*)(Vg + (size_t)(k0 + 64 + kr) * 4608 + ch * 8);
    }

    // LDS gathers + exp (no max-sub; proven exact round 6) + P strip
    float p[2][4];
#pragma unroll
    for (int jj = 0; jj < 2; ++jj) {
      const int k = k0 + (half * 2 + jj) * 16 + l15;
      const bool kvld = k < len;
      const int kloc = (half * 2 + jj) * 16 + l15;
#pragma unroll
      for (int r = 0; r < 4; ++r) {
        const int q = qrb + lhi4 + r;
        const int cc = Tt[q - k + 1023];
        const float rel = bf2f(C2P_[(qg * 16 + lhi4 + r) * 514 + cc])
                        + bf2f(p2cW[kloc * 130 + (cc - cc0)]);
        p[jj][r] = kvld ? __expf(s[jj][r] + rel) : 0.f;
      }
    }
#pragma unroll
    for (int r = 0; r < 4; ++r) lsum[r] += p[0][r] + p[1][r];
#pragma unroll
    for (int jj = 0; jj < 2; ++jj)
#pragma unroll
      for (int r = 0; r < 4; ++r) {
        const int row = lhi4 + r, col = (half * 2 + jj) * 16 + l15;
        myP[row * 64 + (col ^ ((row & 7) * 8))] = f2bf(p[jj][r]);
      }
    bar_lds();                                          // B3: P strips complete

    // PV: O[q][d-half] += P[q][k] V[k][d]
    __builtin_amdgcn_s_setprio(1);
#pragma unroll
    for (int kh = 0; kh < 2; ++kh) {
      bf16x8 pa = *(const bf16x8*)(myP + l15 * 64 + ((kh * 32 + lhi * 8) ^ ((l15 & 7) * 8)));
#pragma unroll
      for (int jj = 0; jj < 2; ++jj) {
        const int d = (half * 2 + jj) * 16 + l15;
        bf16x8 vf = *(const bf16x8*)(&Vt[d * 64 + ((kh * 32 + lhi * 8) ^ svz(d))]);
        o_acc[jj] = __builtin_amdgcn_mfma_f32_16x16x32_bf16(pa, vf, o_acc[jj], 0, 0, 0);
      }
    }
    __builtin_amdgcn_s_setprio(0);
    bar_lds();                                          // B4: Kt/Vt/P reads done

    if (more) {
      writeKV(nk, nv);                                  // K/V(kt+1) -> LDS
      cc0 = min((int)Tt[q0 - (k0 + 64) - 63 + 1023], P2c - 128);
      stagePosQ(cc0);                                   // PosQw(kt+1), in flight to next B1
    }
  }

  // ---------- epilogue: combine row-sums across the wave pair, normalize, store ----------
#pragma unroll
  for (int r = 0; r < 4; ++r) {
    float l = lsum[r];
#pragma unroll
    for (int off = 1; off <= 8; off <<= 1) l += __shfl_xor(l, off);
    lsum[r] = l;                                        // sum over this half's 32 k per tile
  }
  float* scr = (float*)&Pl[0][0];                       // 8 KB f32 scratch
#pragma unroll
  for (int r = 0; r < 4; ++r) scr[(wid * 64 + lane) * 4 + r] = lsum[r];
  bar_lds();
#pragma unroll
  for (int r = 0; r < 4; ++r) {
    const float tot = lsum[r] + scr[(((wid ^ 4) * 64) + lane) * 4 + r];
    const int q = qrb + lhi4 + r;
    const float inv = (q < len && tot > 0.f) ? 1.f / tot : 0.f;
#pragma unroll
    for (int jj = 0; jj < 2; ++jj)
      ctx[(size_t)(b * Sc + q) * Hc + h * 64 + (half * 2 + jj) * 16 + l15] =
          f2bf(o_acc[jj][r] * inv);
  }
}

// ---------------- row-wise LayerNorm in-place on d_out ----------------
__global__ __launch_bounds__(256) void ln_kernel(float* __restrict__ io,
    const float* __restrict__ g, const float* __restrict__ bta)
{
  const int row = blockIdx.x;
  float* p = io + (size_t)row * Hc;
  const int tid = threadIdx.x, wid = tid >> 6, lane = tid & 63;
  float v[6];
  float s = 0.f;
#pragma unroll
  for (int j = 0; j < 6; ++j) { v[j] = p[tid + j * 256]; s += v[j]; }
#pragma unroll
  for (int off = 1; off <= 32; off <<= 1) s += __shfl_xor(s, off);
  __shared__ float red[4];
  if (lane == 0) red[wid] = s;
  __syncthreads();
  const float mu = (red[0] + red[1] + red[2] + red[3]) * (1.f / Hc);
  float q = 0.f;
#pragma unroll
  for (int j = 0; j < 6; ++j) { const float d = v[j] - mu; q += d * d; }
#pragma unroll
  for (int off = 1; off <= 32; off <<= 1) q += __shfl_xor(q, off);
  __syncthreads();
  if (lane == 0) red[wid] = q;
  __syncthreads();
  const float rstd = rsqrtf((red[0] + red[1] + red[2] + red[3]) * (1.f / Hc) + 1e-7f);
#pragma unroll
  for (int j = 0; j < 6; ++j) {
    const int c = tid + j * 256;
    p[c] = (v[j] - mu) * rstd * g[c] + bta[c];
  }
}

// ---------------- host launcher ----------------
extern "C" void kernel_launch(void* const* d_in, const int* in_sizes, int n_in,
                              void* d_out, int out_size, void* d_ws, size_t ws_size,
                              hipStream_t stream)
{
  (void)in_sizes; (void)n_in; (void)out_size; (void)ws_size;
  const float* hidden = (const float*)d_in[0];
  const float* relemb = (const float*)d_in[1];
  const float* Wq = (const float*)d_in[2];
  const float* bq = (const float*)d_in[3];
  const float* Wk = (const float*)d_in[4];
  const float* bk = (const float*)d_in[5];
  const float* Wv = (const float*)d_in[6];
  const float* bv = (const float*)d_in[7];
  const float* Wo = (const float*)d_in[8];
  const float* bo = (const float*)d_in[9];
  const float* lng = (const float*)d_in[10];
  const float* lnb = (const float*)d_in[11];
  const int* am = (const int*)d_in[12];
  const int* rp = (const int*)d_in[13];
  float* out = (float*)d_out;

  char* ws = (char*)d_ws;
  size_t off = 0;
  auto alloc = [&](size_t bytes) { size_t r = off; off += (bytes + 255) & ~(size_t)255; return r; };
  const size_t o_qkvp = alloc((size_t)MA * 4608 * 2);
  const size_t o_wt   = alloc((size_t)N3 * Hc * 2);
  const size_t o_wot  = alloc((size_t)Hc * Hc * 2);
  const size_t o_abig = alloc((size_t)MA * Hc * 2);
  const size_t o_bias = alloc((size_t)N3 * 4);
  const size_t o_valid= alloc((size_t)MX * 4);
  const size_t o_tbl  = alloc(2048 * 2);
  const size_t o_lens = alloc(256);

  u16* QKVP = (u16*)(ws + o_qkvp);
  u16* WT   = (u16*)(ws + o_wt);
  u16* WOT  = (u16*)(ws + o_wot);
  u16* ABIG = (u16*)(ws + o_abig);
  u16* CTX  = (u16*)(ws + o_abig);                      // alias: ABIG dead after gemm<0>
  float* BIAS = (float*)(ws + o_bias);
  int* VALID  = (int*)(ws + o_valid);
  u16* TBL  = (u16*)(ws + o_tbl);
  int* LENS = (int*)(ws + o_lens);

  prep_misc<<<dim3(50), dim3(256), 0, stream>>>(bq, bk, bv, am, rp, BIAS, VALID, TBL);
  len_kernel<<<dim3(1), dim3(256), 0, stream>>>(VALID, LENS);
  cast_x<<<dim3(1728), dim3(256), 0, stream>>>(hidden, relemb, ABIG);
  transpose_cast<<<dim3(48, 48, 4), dim3(32, 8), 0, stream>>>(Wq, Wk, Wv, Wo, WT, WOT);
  gemm128<0><<<dim3(36, 36), dim3(256), 0, stream>>>(ABIG, WT, BIAS, (const float*)nullptr,
                                                     QKVP, (float*)nullptr, 4608);
  flash7<<<dim3(1536), dim3(512), 0, stream>>>(QKVP, LENS, TBL, CTX);
  gemm128<1><<<dim3(12, 32), dim3(256), 0, stream>>>(CTX, WOT, bo, hidden,
                                                     (u16*)nullptr, out, Hc);
  ln_kernel<<<dim3(MX), dim3(256), 0, stream>>>(out, lng, lnb);
}